// Round 20
// baseline (895.745 us; speedup 1.0000x reference)
//
#include <hip/hip_runtime.h>
#include <hip/hip_bf16.h>

using f32x4  = __attribute__((ext_vector_type(4))) float;
using bf16x8 = __attribute__((ext_vector_type(8))) short;
using short8 = __attribute__((ext_vector_type(8))) short;
using s16x4  = __attribute__((ext_vector_type(4))) short;

#define DEVINL __device__ __forceinline__

DEVINL short f2bf(float f) {
  unsigned u = __builtin_bit_cast(unsigned, f);
  u += 0x7fffu + ((u >> 16) & 1u);          // RNE
  return (short)(u >> 16);
}

// tanh-approx GELU in sigmoid form: 0.5v(1+tanh(u)) == v/(1+exp(-2u))
DEVINL float gelu_fast(float v) {
  float t = __expf(-1.5957691216057308f * (v + 0.044715f * v * v * v));
  return v * __builtin_amdgcn_rcpf(1.0f + t);
}

#define GLDS16(g, l) __builtin_amdgcn_global_load_lds( \
    (const __attribute__((address_space(1))) void*)(g), \
    (__attribute__((address_space(3))) void*)(l), 16, 0, 0)

// ---------------------------------------------------------------- transpose
__global__ __launch_bounds__(256)
void transpose_bf16(const float* __restrict__ in, short* __restrict__ out, int R, int C) {
  int idx = blockIdx.x * 256 + threadIdx.x;
  if (idx >= R * C) return;
  int c = idx / R, r = idx % R;
  out[idx] = f2bf(in[(size_t)r * C + c]);
}

// ---------------------------------------------------------------- bias expand
__global__ __launch_bounds__(256)
void bias_expand(const float* __restrict__ rpb, float* __restrict__ BIASF) {
  int idx = blockIdx.x * 256 + threadIdx.x;   // 65536
  int head = idx >> 12, n = (idx >> 6) & 63, m = idx & 63;
  int i1 = n >> 3, j1 = n & 7, i2 = m >> 3, j2 = m & 7;
  BIASF[idx] = rpb[((i1 - i2 + 7) * 15 + (j1 - j2 + 7)) * 16 + head];
}

// ---------------------------------------------------------------- LayerNorm
template<int REMAP>
__global__ __launch_bounds__(256)
void ln_kernel(const float* __restrict__ X, const float* __restrict__ gamma,
               const float* __restrict__ beta, short* __restrict__ OUT) {
  const int lane = threadIdx.x & 63;
  const int wid  = threadIdx.x >> 6;
  const int t    = blockIdx.x * 4 + wid;
  const float* xp = X + (size_t)t * 512 + lane * 8;
  float4 a = *(const float4*)xp;
  float4 b = *(const float4*)(xp + 4);
  float s = a.x + a.y + a.z + a.w + b.x + b.y + b.z + b.w;
  float q = a.x*a.x + a.y*a.y + a.z*a.z + a.w*a.w
          + b.x*b.x + b.y*b.y + b.z*b.z + b.w*b.w;
#pragma unroll
  for (int d = 1; d < 64; d <<= 1) { s += __shfl_xor(s, d); q += __shfl_xor(q, d); }
  float mean = s * (1.0f / 512.0f);
  float var  = q * (1.0f / 512.0f) - mean * mean;
  float rstd = rsqrtf(var + 1e-5f);
  float4 g0 = *(const float4*)(gamma + lane * 8);
  float4 g1 = *(const float4*)(gamma + lane * 8 + 4);
  float4 b0 = *(const float4*)(beta + lane * 8);
  float4 b1 = *(const float4*)(beta + lane * 8 + 4);
  short8 o;
  o[0] = f2bf((a.x - mean) * rstd * g0.x + b0.x);
  o[1] = f2bf((a.y - mean) * rstd * g0.y + b0.y);
  o[2] = f2bf((a.z - mean) * rstd * g0.z + b0.z);
  o[3] = f2bf((a.w - mean) * rstd * g0.w + b0.w);
  o[4] = f2bf((b.x - mean) * rstd * g1.x + b1.x);
  o[5] = f2bf((b.y - mean) * rstd * g1.y + b1.y);
  o[6] = f2bf((b.z - mean) * rstd * g1.z + b1.z);
  o[7] = f2bf((b.w - mean) * rstd * g1.w + b1.w);
  size_t orow;
  if (REMAP) {
    int bb = t >> 12, l = t & 4095, hh = l >> 6, ww = l & 63;
    int hs = (hh + 60) & 63, ws2 = (ww + 60) & 63;   // (coord - 4) mod 64
    orow = (size_t)(bb * 64 + (hs >> 3) * 8 + (ws2 >> 3)) * 64 + (hs & 7) * 8 + (ws2 & 7);
  } else {
    orow = (size_t)t;
  }
  *(short8*)(OUT + orow * 512 + lane * 8) = o;
}

// ---------------------------------------------------------------- attention core
__global__ __launch_bounds__(256)
void attn_core(const short* __restrict__ Q, const short* __restrict__ Kb,
               const short* __restrict__ VT, const float* __restrict__ BIASF,
               short* __restrict__ AOUT) {
  __shared__ short P[4][4096];
  const int tid = threadIdx.x, lane = tid & 63, wid = tid >> 6;
  const int lr = lane & 15, lg = lane >> 4;
  const int gw = blockIdx.x * 4 + wid;
  const int win = gw >> 4, head = gw & 15;
  const int wimg = win & 63, wh = wimg >> 3, ww = wimg & 7;
  const size_t qbase = (size_t)win * 64 * 512 + head * 32;
  short* Pb = P[wid];

  bf16x8 aq[4], bk[4];
#pragma unroll
  for (int tm = 0; tm < 4; ++tm) aq[tm] = *(const bf16x8*)(Q  + qbase + (size_t)(tm * 16 + lr) * 512 + lg * 8);
#pragma unroll
  for (int tn = 0; tn < 4; ++tn) bk[tn] = *(const bf16x8*)(Kb + qbase + (size_t)(tn * 16 + lr) * 512 + lg * 8);
  f32x4 sa[4][4] = {};
#pragma unroll
  for (int tm = 0; tm < 4; ++tm)
#pragma unroll
    for (int tn = 0; tn < 4; ++tn)
      sa[tm][tn] = __builtin_amdgcn_mfma_f32_16x16x32_bf16(aq[tm], bk[tn], sa[tm][tn], 0, 0, 0);

  const float* bias_h = BIASF + head * 4096;
  float inv[4][4];
#pragma unroll
  for (int tm = 0; tm < 4; ++tm) {
#pragma unroll
    for (int e = 0; e < 4; ++e) {
      const int n = tm * 16 + lg * 4 + e;
      const int i1 = n >> 3, j1 = n & 7;
      const int rh1 = (wh == 7) ? 1 + (i1 >> 2) : 0;
      const int rw1 = (ww == 7) ? 1 + (j1 >> 2) : 0;
      float v[4];
      float mx = -3.0e38f;
#pragma unroll
      for (int tn = 0; tn < 4; ++tn) {
        const int m = tn * 16 + lr;
        const int mi = (m >> 3), mj = m & 7;
        const int rh2 = (wh == 7) ? 1 + (mi >> 2) : 0;
        const int rw2 = (ww == 7) ? 1 + (mj >> 2) : 0;
        float val = sa[tm][tn][e] + bias_h[n * 64 + m]
                  + ((rh1 != rh2 || rw1 != rw2) ? -100.0f : 0.0f);
        v[tn] = val;
        mx = fmaxf(mx, val);
      }
#pragma unroll
      for (int d = 1; d < 16; d <<= 1) mx = fmaxf(mx, __shfl_xor(mx, d));
      float sum = 0.f;
#pragma unroll
      for (int tn = 0; tn < 4; ++tn) { v[tn] = __expf(v[tn] - mx); sum += v[tn]; }
#pragma unroll
      for (int d = 1; d < 16; d <<= 1) sum += __shfl_xor(sum, d);
      inv[tm][e] = 1.0f / sum;
      const int sw = (n & 7) << 3;
#pragma unroll
      for (int tn = 0; tn < 4; ++tn) Pb[n * 64 + ((tn * 16 + lr) ^ sw)] = f2bf(v[tn]);
    }
  }
  __syncthreads();

  f32x4 oa[4][2] = {};
  const short* vt = VT + (size_t)win * 32768 + head * 2048;
#pragma unroll
  for (int ks = 0; ks < 2; ++ks) {
    bf16x8 pa[4], bv[2];
#pragma unroll
    for (int tm = 0; tm < 4; ++tm) {
      const int r = tm * 16 + lr;
      pa[tm] = *(const bf16x8*)(Pb + r * 64 + ((ks * 32 + lg * 8) ^ ((r & 7) << 3)));
    }
#pragma unroll
    for (int t2 = 0; t2 < 2; ++t2) bv[t2] = *(const bf16x8*)(vt + (t2 * 16 + lr) * 64 + ks * 32 + lg * 8);
#pragma unroll
    for (int tm = 0; tm < 4; ++tm)
#pragma unroll
      for (int t2 = 0; t2 < 2; ++t2)
        oa[tm][t2] = __builtin_amdgcn_mfma_f32_16x16x32_bf16(pa[tm], bv[t2], oa[tm][t2], 0, 0, 0);
  }
#pragma unroll
  for (int tm = 0; tm < 4; ++tm)
#pragma unroll
    for (int t2 = 0; t2 < 2; ++t2)
#pragma unroll
      for (int e = 0; e < 4; ++e) {
        const int n = tm * 16 + lg * 4 + e;
        AOUT[((size_t)win * 64 + n) * 512 + head * 32 + t2 * 16 + lr] = f2bf(oa[tm][t2][e] * inv[tm][e]);
      }
}

// ---------------------------------------------------------------- 128x128 GEMM, BK=64, 4 blocks/CU
// R17's schedule (BK=64: 32 MFMA/wave per drain, 1 barrier pair per K-tile,
// both-sides row&7 swizzle on 128B rows) at 128x128 tile / 256 threads:
// LDS 32KB + ~64 arch VGPR + 64 acc -> 4 blocks/CU co-resident (vs R17's 2).
// The only variable vs the 843us best is block-level TLP on the drain.
// Staging: 8 GLDS16/thread; instr c of A covers row c*32+(tid>>3), slot tid&7;
// source col pre-swizzled ((tid&7)^((tid>>3)&7))*8 (32 = 0 mod 8 keeps it
// c-invariant); read slot = (kk*4+lg)^(lr&7). 4 waves (2m x 2n), tile 64x64.
template<int EPI, int K, int NX>
__global__ __launch_bounds__(256)
void gemmTLP(const short* __restrict__ Aa, const short* __restrict__ Bb,
             const float* __restrict__ bias, const float* __restrict__ resid,
             float* __restrict__ outf, short* __restrict__ outh) {
  constexpr int NT = K / 64;
  __shared__ short L[16384];   // A bytes [0,16384), B bytes [16384,32768)
  const int tid = threadIdx.x;
  const int lane = tid & 63, wid = tid >> 6;
  const int lr = lane & 15, lg = lane >> 4;
  const int wm = wid >> 1, wn = wid & 1;

  // XCD-aware bijective swizzle (all grids are multiples of 8)
  const int nwg = gridDim.x;
  const int id = blockIdx.x;
  const int id2 = (id & 7) * (nwg >> 3) + (id >> 3);
  const int mt    = (EPI == 1) ? (id2 % NX) : (id2 / NX);
  const int ntile = (EPI == 1) ? (id2 / NX) : (id2 % NX);
  const int m0 = mt * 128, n0 = ntile * 128;

  // staging geometry: instr c -> row c*32 + rr, phys slot tid&7
  const int rr = tid >> 3;                                   // 0..31
  const int ss = ((tid & 7) ^ (rr & 7)) * 8;                 // swizzled source col (elems)
  const short* pA = Aa + (size_t)(m0 + rr) * K + ss;
  const short* pB = Bb + (size_t)(n0 + rr) * K + ss;
  char* Ld = (char*)L + tid * 16;

  // frag read bases (slot = (kk*4+lg)^(lr&7))
  const int xr = lr & 7;
  const char* rA0 = (char*)L + (wm * 64 + lr) * 128 + ((lg ^ xr) << 4);
  const char* rA1 = (char*)L + (wm * 64 + lr) * 128 + (((4 + lg) ^ xr) << 4);
  const char* rB0 = (char*)L + 16384 + (wn * 64 + lr) * 128 + ((lg ^ xr) << 4);
  const char* rB1 = (char*)L + 16384 + (wn * 64 + lr) * 128 + (((4 + lg) ^ xr) << 4);

  f32x4 acc[4][4] = {};
  for (int kt = 0; kt < NT; ++kt) {
    const int ko = kt * 64;
    GLDS16(pA + ko,                   Ld);
    GLDS16(pA + ko + (size_t)32 * K,  Ld + 4096);
    GLDS16(pA + ko + (size_t)64 * K,  Ld + 8192);
    GLDS16(pA + ko + (size_t)96 * K,  Ld + 12288);
    GLDS16(pB + ko,                   Ld + 16384);
    GLDS16(pB + ko + (size_t)32 * K,  Ld + 20480);
    GLDS16(pB + ko + (size_t)64 * K,  Ld + 24576);
    GLDS16(pB + ko + (size_t)96 * K,  Ld + 28672);
    __syncthreads();
    bf16x8 a[4], b[4];
#pragma unroll
    for (int i = 0; i < 4; ++i) a[i] = *(const bf16x8*)(rA0 + i * 2048);
#pragma unroll
    for (int j = 0; j < 4; ++j) b[j] = *(const bf16x8*)(rB0 + j * 2048);
#pragma unroll
    for (int i = 0; i < 4; ++i)
#pragma unroll
      for (int j = 0; j < 4; ++j)
        acc[i][j] = __builtin_amdgcn_mfma_f32_16x16x32_bf16(a[i], b[j], acc[i][j], 0, 0, 0);
#pragma unroll
    for (int i = 0; i < 4; ++i) a[i] = *(const bf16x8*)(rA1 + i * 2048);
#pragma unroll
    for (int j = 0; j < 4; ++j) b[j] = *(const bf16x8*)(rB1 + j * 2048);
#pragma unroll
    for (int i = 0; i < 4; ++i)
#pragma unroll
      for (int j = 0; j < 4; ++j)
        acc[i][j] = __builtin_amdgcn_mfma_f32_16x16x32_bf16(a[i], b[j], acc[i][j], 0, 0, 0);
    __syncthreads();
  }

  // ---- epilogue (col = n0+wn*64+j*16+lr, row = m0+wm*64+i*16+lg*4+e)
  if (EPI == 1) {
    // fc1 swapped: C row = h, col = tok; pack 4 consecutive h
#pragma unroll
    for (int i = 0; i < 4; ++i) {
      const int h0 = m0 + wm * 64 + i * 16 + lg * 4;
      const float4 bi = *(const float4*)(bias + h0);
#pragma unroll
      for (int j = 0; j < 4; ++j) {
        const int tok = n0 + wn * 64 + j * 16 + lr;
        s16x4 o;
        o[0] = f2bf(gelu_fast(acc[i][j][0] + bi.x));
        o[1] = f2bf(gelu_fast(acc[i][j][1] + bi.y));
        o[2] = f2bf(gelu_fast(acc[i][j][2] + bi.z));
        o[3] = f2bf(gelu_fast(acc[i][j][3] + bi.w));
        *(s16x4*)(outh + (size_t)tok * 2048 + h0) = o;
      }
    }
  } else if (EPI == 0) {
#pragma unroll
    for (int j = 0; j < 4; ++j) {
      const int col = n0 + wn * 64 + j * 16 + lr;
      const float bc = bias[col];
#pragma unroll
      for (int i = 0; i < 4; ++i)
#pragma unroll
        for (int e = 0; e < 4; ++e) {
          const int row = m0 + wm * 64 + i * 16 + lg * 4 + e;
          float v = acc[i][j][e] + bc;
          const int wv = row >> 6, n = row & 63;
          const int bb = wv >> 6, wi = wv & 63;
          const int hs = (wi >> 3) * 8 + (n >> 3), ws2 = (wi & 7) * 8 + (n & 7);
          const int hh = (hs + 4) & 63, wwp = (ws2 + 4) & 63;
          const size_t orow = (size_t)bb * 4096 + hh * 64 + wwp;
          outf[orow * 512 + col] = resid[orow * 512 + col] + v;
        }
    }
  } else if (EPI == 2) {
#pragma unroll
    for (int j = 0; j < 4; ++j) {
      const int col = n0 + wn * 64 + j * 16 + lr;
      const float bc = bias[col];
#pragma unroll
      for (int i = 0; i < 4; ++i)
#pragma unroll
        for (int e = 0; e < 4; ++e) {
          const int row = m0 + wm * 64 + i * 16 + lg * 4 + e;
          outf[(size_t)row * 512 + col] = acc[i][j][e] + bc + resid[(size_t)row * 512 + col];
        }
    }
  } else {
    // qkv: seg uniform per block (n-tile of 128 never straddles a 512-col segment)
    const int seg = n0 >> 9;
#pragma unroll
    for (int j = 0; j < 4; ++j) {
      const int col = n0 + wn * 64 + j * 16 + lr;
      const float bc = bias[col];
#pragma unroll
      for (int i = 0; i < 4; ++i) {
        const int row0 = m0 + wm * 64 + i * 16 + lg * 4;
        if (seg == 2) {
          const int cc = col - 1024;                 // V^T packed 8B store (e-dim = tok)
          s16x4 o;
#pragma unroll
          for (int e = 0; e < 4; ++e) o[e] = f2bf(acc[i][j][e] + bc);
          *(s16x4*)(outh + 67108864 +
                    (size_t)((row0 >> 6) * 16 + (cc >> 5)) * 2048 + (cc & 31) * 64 + (row0 & 63)) = o;
        } else {
#pragma unroll
          for (int e = 0; e < 4; ++e) {
            const int row = row0 + e;
            float v = acc[i][j][e] + bc;
            if (seg == 0) outh[(size_t)row * 512 + col] = f2bf(v * 0.17677669529663687f);
            else          outh[33554432 + (size_t)row * 512 + (col - 512)] = f2bf(v);
          }
        }
      }
    }
  }
}

// ---------------------------------------------------------------- launch
extern "C" void kernel_launch(void* const* d_in, const int* in_sizes, int n_in,
                              void* d_out, int out_size, void* d_ws, size_t ws_size,
                              hipStream_t stream) {
  (void)in_sizes; (void)n_in; (void)out_size; (void)ws_size;
  const float* x      = (const float*)d_in[0];
  const float* g1     = (const float*)d_in[1];
  const float* b1     = (const float*)d_in[2];
  const float* qkv_w  = (const float*)d_in[3];
  const float* qkv_b  = (const float*)d_in[4];
  const float* proj_w = (const float*)d_in[5];
  const float* proj_b = (const float*)d_in[6];
  const float* rpb    = (const float*)d_in[7];
  const float* g2     = (const float*)d_in[8];
  const float* b2     = (const float*)d_in[9];
  const float* fc1_w  = (const float*)d_in[10];
  const float* fc1_b  = (const float*)d_in[11];
  const float* fc2_w  = (const float*)d_in[12];
  const float* fc2_b  = (const float*)d_in[13];
  float* out = (float*)d_out;
  char* ws = (char*)d_ws;

  short* WQKVT  = (short*)(ws);                 // [1536][512] bf16   1.5MB
  short* WPROJT = (short*)(ws + 1572864);       // [512][512]         0.5MB
  short* WFC1T  = (short*)(ws + 2097152);       // [2048][512]        2MB
  short* WFC2T  = (short*)(ws + 4194304);       // [512][2048]        2MB
  float* X2     = (float*)(ws + 6291456);       // [65536][512] fp32  134MB
  float* BIASF  = (float*)(ws + 6291456);       // 256KB alias (dead before proj)
  short* ATT    = (short*)(ws + 140509184);     // [65536][512] bf16  64MB (X2N reuse)
  short* XW     = (short*)(ws + 207618048);     // [65536][512] bf16  64MB
  short* QB     = (short*)(ws + 274726912);     // Q|K|VT 3x64MB
  short* H1     = XW;                           // [65536][2048] bf16 256MB over XW+QB (dead)
  short* X2N    = ATT;

  transpose_bf16<<<3072, 256, 0, stream>>>(qkv_w,  WQKVT, 512, 1536);
  transpose_bf16<<<1024, 256, 0, stream>>>(proj_w, WPROJT, 512, 512);
  transpose_bf16<<<4096, 256, 0, stream>>>(fc1_w,  WFC1T, 512, 2048);
  transpose_bf16<<<4096, 256, 0, stream>>>(fc2_w,  WFC2T, 2048, 512);
  bias_expand<<<256, 256, 0, stream>>>(rpb, BIASF);

  ln_kernel<1><<<16384, 256, 0, stream>>>(x, g1, b1, XW);
  // qkv: A=XW (512 m-tiles), BT=WQKVT (12 n-tiles)
  gemmTLP<3, 512, 12><<<6144, 256, 0, stream>>>(XW, WQKVT, qkv_b, nullptr, nullptr, QB);
  attn_core<<<4096, 256, 0, stream>>>(QB, QB + 33554432, QB + 67108864, BIASF, ATT);
  // proj: A=ATT (512 m-tiles), BT=WPROJT (4 n-tiles) -> X2 (window-reverse + x resid)
  gemmTLP<0, 512, 4><<<2048, 256, 0, stream>>>(ATT, WPROJT, proj_b, x, X2, nullptr);
  ln_kernel<0><<<16384, 256, 0, stream>>>(X2, g2, b2, X2N);
  // fc1 swapped: A=W1T (16 m-tiles), B=X2N (512 n-tiles) -> H1[tok][2048]
  gemmTLP<1, 512, 16><<<8192, 256, 0, stream>>>(WFC1T, X2N, fc1_b, nullptr, nullptr, H1);
  // fc2: A=H1 (512 m-tiles), BT=W2T (4 n-tiles) -> out + bias + X2 resid
  gemmTLP<2, 2048, 4><<<2048, 256, 0, stream>>>(H1, WFC2T, fc2_b, X2, out, nullptr);
}

// Round 21
// 846.066 us; speedup vs baseline: 1.0587x; 1.0587x over previous
//
#include <hip/hip_runtime.h>
#include <hip/hip_bf16.h>

using f32x4  = __attribute__((ext_vector_type(4))) float;
using bf16x8 = __attribute__((ext_vector_type(8))) short;
using short8 = __attribute__((ext_vector_type(8))) short;
using s16x4  = __attribute__((ext_vector_type(4))) short;

#define DEVINL __device__ __forceinline__

DEVINL short f2bf(float f) {
  unsigned u = __builtin_bit_cast(unsigned, f);
  u += 0x7fffu + ((u >> 16) & 1u);          // RNE
  return (short)(u >> 16);
}

// tanh-approx GELU in sigmoid form: 0.5v(1+tanh(u)) == v/(1+exp(-2u))
DEVINL float gelu_fast(float v) {
  float t = __expf(-1.5957691216057308f * (v + 0.044715f * v * v * v));
  return v * __builtin_amdgcn_rcpf(1.0f + t);
}

#define GLDS16(g, l) __builtin_amdgcn_global_load_lds( \
    (const __attribute__((address_space(1))) void*)(g), \
    (__attribute__((address_space(3))) void*)(l), 16, 0, 0)

// ---------------------------------------------------------------- fused prep
// One launch: 4 weight transposes (fp32 -> bf16, B^T layouts) + rpb bias expand.
__global__ __launch_bounds__(256)
void prep(const float* __restrict__ qkv_w, const float* __restrict__ proj_w,
          const float* __restrict__ fc1_w, const float* __restrict__ fc2_w,
          const float* __restrict__ rpb,
          short* __restrict__ WQKVT, short* __restrict__ WPROJT,
          short* __restrict__ WFC1T, short* __restrict__ WFC2T,
          float* __restrict__ BIASF) {
  const int b = blockIdx.x, t = threadIdx.x;
  if (b < 3072) {                 // WQKVT [1536][512] <- qkv_w [512][1536]
    int idx = b * 256 + t; int c = idx / 512, r = idx % 512;
    WQKVT[idx] = f2bf(qkv_w[(size_t)r * 1536 + c]);
  } else if (b < 4096) {          // WPROJT [512][512] <- proj_w [512][512]
    int idx = (b - 3072) * 256 + t; int c = idx / 512, r = idx % 512;
    WPROJT[idx] = f2bf(proj_w[(size_t)r * 512 + c]);
  } else if (b < 8192) {          // WFC1T [2048][512] <- fc1_w [512][2048]
    int idx = (b - 4096) * 256 + t; int c = idx / 512, r = idx % 512;
    WFC1T[idx] = f2bf(fc1_w[(size_t)r * 2048 + c]);
  } else if (b < 12288) {         // WFC2T [512][2048] <- fc2_w [2048][512]
    int idx = (b - 8192) * 256 + t; int c = idx / 2048, r = idx % 2048;
    WFC2T[idx] = f2bf(fc2_w[(size_t)r * 512 + c]);
  } else {                        // BIASF[head][n][m]
    int idx = (b - 12288) * 256 + t;
    int head = idx >> 12, n = (idx >> 6) & 63, m = idx & 63;
    int i1 = n >> 3, j1 = n & 7, i2 = m >> 3, j2 = m & 7;
    BIASF[idx] = rpb[((i1 - i2 + 7) * 15 + (j1 - j2 + 7)) * 16 + head];
  }
}

// ---------------------------------------------------------------- LayerNorm
template<int REMAP>
__global__ __launch_bounds__(256)
void ln_kernel(const float* __restrict__ X, const float* __restrict__ gamma,
               const float* __restrict__ beta, short* __restrict__ OUT) {
  const int lane = threadIdx.x & 63;
  const int wid  = threadIdx.x >> 6;
  const int t    = blockIdx.x * 4 + wid;
  const float* xp = X + (size_t)t * 512 + lane * 8;
  float4 a = *(const float4*)xp;
  float4 b = *(const float4*)(xp + 4);
  float s = a.x + a.y + a.z + a.w + b.x + b.y + b.z + b.w;
  float q = a.x*a.x + a.y*a.y + a.z*a.z + a.w*a.w
          + b.x*b.x + b.y*b.y + b.z*b.z + b.w*b.w;
#pragma unroll
  for (int d = 1; d < 64; d <<= 1) { s += __shfl_xor(s, d); q += __shfl_xor(q, d); }
  float mean = s * (1.0f / 512.0f);
  float var  = q * (1.0f / 512.0f) - mean * mean;
  float rstd = rsqrtf(var + 1e-5f);
  float4 g0 = *(const float4*)(gamma + lane * 8);
  float4 g1 = *(const float4*)(gamma + lane * 8 + 4);
  float4 b0 = *(const float4*)(beta + lane * 8);
  float4 b1 = *(const float4*)(beta + lane * 8 + 4);
  short8 o;
  o[0] = f2bf((a.x - mean) * rstd * g0.x + b0.x);
  o[1] = f2bf((a.y - mean) * rstd * g0.y + b0.y);
  o[2] = f2bf((a.z - mean) * rstd * g0.z + b0.z);
  o[3] = f2bf((a.w - mean) * rstd * g0.w + b0.w);
  o[4] = f2bf((b.x - mean) * rstd * g1.x + b1.x);
  o[5] = f2bf((b.y - mean) * rstd * g1.y + b1.y);
  o[6] = f2bf((b.z - mean) * rstd * g1.z + b1.z);
  o[7] = f2bf((b.w - mean) * rstd * g1.w + b1.w);
  size_t orow;
  if (REMAP) {
    int bb = t >> 12, l = t & 4095, hh = l >> 6, ww = l & 63;
    int hs = (hh + 60) & 63, ws2 = (ww + 60) & 63;   // (coord - 4) mod 64
    orow = (size_t)(bb * 64 + (hs >> 3) * 8 + (ws2 >> 3)) * 64 + (hs & 7) * 8 + (ws2 & 7);
  } else {
    orow = (size_t)t;
  }
  *(short8*)(OUT + orow * 512 + lane * 8) = o;
}

// ---------------------------------------------------------------- attention core
__global__ __launch_bounds__(256)
void attn_core(const short* __restrict__ Q, const short* __restrict__ Kb,
               const short* __restrict__ VT, const float* __restrict__ BIASF,
               short* __restrict__ AOUT) {
  __shared__ short P[4][4096];
  const int tid = threadIdx.x, lane = tid & 63, wid = tid >> 6;
  const int lr = lane & 15, lg = lane >> 4;
  const int gw = blockIdx.x * 4 + wid;
  const int win = gw >> 4, head = gw & 15;
  const int wimg = win & 63, wh = wimg >> 3, ww = wimg & 7;
  const size_t qbase = (size_t)win * 64 * 512 + head * 32;
  short* Pb = P[wid];

  bf16x8 aq[4], bk[4];
#pragma unroll
  for (int tm = 0; tm < 4; ++tm) aq[tm] = *(const bf16x8*)(Q  + qbase + (size_t)(tm * 16 + lr) * 512 + lg * 8);
#pragma unroll
  for (int tn = 0; tn < 4; ++tn) bk[tn] = *(const bf16x8*)(Kb + qbase + (size_t)(tn * 16 + lr) * 512 + lg * 8);
  f32x4 sa[4][4] = {};
#pragma unroll
  for (int tm = 0; tm < 4; ++tm)
#pragma unroll
    for (int tn = 0; tn < 4; ++tn)
      sa[tm][tn] = __builtin_amdgcn_mfma_f32_16x16x32_bf16(aq[tm], bk[tn], sa[tm][tn], 0, 0, 0);

  const float* bias_h = BIASF + head * 4096;
  float inv[4][4];
#pragma unroll
  for (int tm = 0; tm < 4; ++tm) {
#pragma unroll
    for (int e = 0; e < 4; ++e) {
      const int n = tm * 16 + lg * 4 + e;
      const int i1 = n >> 3, j1 = n & 7;
      const int rh1 = (wh == 7) ? 1 + (i1 >> 2) : 0;
      const int rw1 = (ww == 7) ? 1 + (j1 >> 2) : 0;
      float v[4];
      float mx = -3.0e38f;
#pragma unroll
      for (int tn = 0; tn < 4; ++tn) {
        const int m = tn * 16 + lr;
        const int mi = (m >> 3), mj = m & 7;
        const int rh2 = (wh == 7) ? 1 + (mi >> 2) : 0;
        const int rw2 = (ww == 7) ? 1 + (mj >> 2) : 0;
        float val = sa[tm][tn][e] + bias_h[n * 64 + m]
                  + ((rh1 != rh2 || rw1 != rw2) ? -100.0f : 0.0f);
        v[tn] = val;
        mx = fmaxf(mx, val);
      }
#pragma unroll
      for (int d = 1; d < 16; d <<= 1) mx = fmaxf(mx, __shfl_xor(mx, d));
      float sum = 0.f;
#pragma unroll
      for (int tn = 0; tn < 4; ++tn) { v[tn] = __expf(v[tn] - mx); sum += v[tn]; }
#pragma unroll
      for (int d = 1; d < 16; d <<= 1) sum += __shfl_xor(sum, d);
      inv[tm][e] = 1.0f / sum;
      const int sw = (n & 7) << 3;
#pragma unroll
      for (int tn = 0; tn < 4; ++tn) Pb[n * 64 + ((tn * 16 + lr) ^ sw)] = f2bf(v[tn]);
    }
  }
  __syncthreads();

  f32x4 oa[4][2] = {};
  const short* vt = VT + (size_t)win * 32768 + head * 2048;
#pragma unroll
  for (int ks = 0; ks < 2; ++ks) {
    bf16x8 pa[4], bv[2];
#pragma unroll
    for (int tm = 0; tm < 4; ++tm) {
      const int r = tm * 16 + lr;
      pa[tm] = *(const bf16x8*)(Pb + r * 64 + ((ks * 32 + lg * 8) ^ ((r & 7) << 3)));
    }
#pragma unroll
    for (int t2 = 0; t2 < 2; ++t2) bv[t2] = *(const bf16x8*)(vt + (t2 * 16 + lr) * 64 + ks * 32 + lg * 8);
#pragma unroll
    for (int tm = 0; tm < 4; ++tm)
#pragma unroll
      for (int t2 = 0; t2 < 2; ++t2)
        oa[tm][t2] = __builtin_amdgcn_mfma_f32_16x16x32_bf16(pa[tm], bv[t2], oa[tm][t2], 0, 0, 0);
  }
#pragma unroll
  for (int tm = 0; tm < 4; ++tm)
#pragma unroll
    for (int t2 = 0; t2 < 2; ++t2)
#pragma unroll
      for (int e = 0; e < 4; ++e) {
        const int n = tm * 16 + lg * 4 + e;
        AOUT[((size_t)win * 64 + n) * 512 + head * 32 + t2 * 16 + lr] = f2bf(oa[tm][t2][e] * inv[tm][e]);
      }
}

// ---------------------------------------------------------------- 256x128 GEMM, BK=64 (R17 structure)
// BK=64: 32 MFMA/wave per drain, 1 barrier pair per K-tile. LDS 48KB -> 2
// blocks/CU; ~64 arch VGPR + 64 acc -> 16 waves/CU (measured 42% occ, 843us).
// Staging: instr c covers row c*64+(tid>>3), slot tid&7; source pre-swizzled
// slot^=(row&7); read slot = (kk*4+lg)^(lr&7). 2-way conflicts = free.
// 8 waves (4m x 2n), wave tile 64x64, row stride 128B.
// EPI 0 (proj): C[tok][out] -> X2 fp32 window-reversed + x residual + bias
// EPI 1 (fc1, swapped): C[h][tok] -> H1[tok][2048] bf16 gelu, packed s16x4
// EPI 2 (fc2): C[tok][out] -> out fp32 = acc + bias + X2 residual
// EPI 3 (qkv, swapped): C[oc][tok] -> Q/K packed s16x4 at [tok][512]; VT d-contig
template<int EPI, int K, int NX>
__global__ __launch_bounds__(512, 1)
void gemmBK64(const short* __restrict__ Aa, const short* __restrict__ Bb,
              const float* __restrict__ bias, const float* __restrict__ resid,
              float* __restrict__ outf, short* __restrict__ outh) {
  constexpr int NT = K / 64;
  __shared__ short L[24576];   // A bytes [0,32768), B bytes [32768,49152)
  const int tid = threadIdx.x;
  const int lane = tid & 63, wid = tid >> 6;
  const int lr = lane & 15, lg = lane >> 4;
  const int wm = wid >> 1, wn = wid & 1;

  // XCD-aware bijective swizzle (all grids are multiples of 8)
  const int nwg = gridDim.x;
  const int id = blockIdx.x;
  const int id2 = (id & 7) * (nwg >> 3) + (id >> 3);
  const bool swapped = (EPI == 1 || EPI == 3);
  const int mt    = swapped ? (id2 % NX) : (id2 / NX);
  const int ntile = swapped ? (id2 / NX) : (id2 % NX);
  const int m0 = mt * 256, n0 = ntile * 128;

  // staging geometry: instr c -> row c*64 + rr, phys slot tid&7
  const int rr = tid >> 3;                                   // 0..63
  const int ss = ((tid & 7) ^ (rr & 7)) * 8;                 // swizzled source col (elems)
  const short* pA = Aa + (size_t)(m0 + rr) * K + ss;
  const short* pB = Bb + (size_t)(n0 + rr) * K + ss;
  char* Ld = (char*)L + tid * 16;

  // frag read bases (slot = (kk*4+lg)^(lr&7))
  const int xr = lr & 7;
  const char* rA0 = (char*)L + (wm * 64 + lr) * 128 + ((lg ^ xr) << 4);
  const char* rA1 = (char*)L + (wm * 64 + lr) * 128 + (((4 + lg) ^ xr) << 4);
  const char* rB0 = (char*)L + 32768 + (wn * 64 + lr) * 128 + ((lg ^ xr) << 4);
  const char* rB1 = (char*)L + 32768 + (wn * 64 + lr) * 128 + (((4 + lg) ^ xr) << 4);

  f32x4 acc[4][4] = {};
  for (int kt = 0; kt < NT; ++kt) {
    const int ko = kt * 64;
    GLDS16(pA + ko,                    Ld);
    GLDS16(pA + ko + (size_t)64  * K,  Ld + 8192);
    GLDS16(pA + ko + (size_t)128 * K,  Ld + 16384);
    GLDS16(pA + ko + (size_t)192 * K,  Ld + 24576);
    GLDS16(pB + ko,                    Ld + 32768);
    GLDS16(pB + ko + (size_t)64  * K,  Ld + 40960);
    __syncthreads();
    bf16x8 a[4], b[4];
#pragma unroll
    for (int i = 0; i < 4; ++i) a[i] = *(const bf16x8*)(rA0 + i * 2048);
#pragma unroll
    for (int j = 0; j < 4; ++j) b[j] = *(const bf16x8*)(rB0 + j * 2048);
#pragma unroll
    for (int i = 0; i < 4; ++i)
#pragma unroll
      for (int j = 0; j < 4; ++j)
        acc[i][j] = __builtin_amdgcn_mfma_f32_16x16x32_bf16(a[i], b[j], acc[i][j], 0, 0, 0);
#pragma unroll
    for (int i = 0; i < 4; ++i) a[i] = *(const bf16x8*)(rA1 + i * 2048);
#pragma unroll
    for (int j = 0; j < 4; ++j) b[j] = *(const bf16x8*)(rB1 + j * 2048);
#pragma unroll
    for (int i = 0; i < 4; ++i)
#pragma unroll
      for (int j = 0; j < 4; ++j)
        acc[i][j] = __builtin_amdgcn_mfma_f32_16x16x32_bf16(a[i], b[j], acc[i][j], 0, 0, 0);
    __syncthreads();
  }

  // ---- epilogue
  if (EPI == 1) {
    // fc1 swapped: C row = h, col = tok; pack 4 consecutive h
#pragma unroll
    for (int i = 0; i < 4; ++i) {
      const int h0 = m0 + wm * 64 + i * 16 + lg * 4;
      const float4 bi = *(const float4*)(bias + h0);
#pragma unroll
      for (int j = 0; j < 4; ++j) {
        const int tok = n0 + wn * 64 + j * 16 + lr;
        s16x4 o;
        o[0] = f2bf(gelu_fast(acc[i][j][0] + bi.x));
        o[1] = f2bf(gelu_fast(acc[i][j][1] + bi.y));
        o[2] = f2bf(gelu_fast(acc[i][j][2] + bi.z));
        o[3] = f2bf(gelu_fast(acc[i][j][3] + bi.w));
        *(s16x4*)(outh + (size_t)tok * 2048 + h0) = o;
      }
    }
  } else if (EPI == 0) {
#pragma unroll
    for (int j = 0; j < 4; ++j) {
      const int col = n0 + wn * 64 + j * 16 + lr;
      const float bc = bias[col];
#pragma unroll
      for (int i = 0; i < 4; ++i)
#pragma unroll
        for (int e = 0; e < 4; ++e) {
          const int row = m0 + wm * 64 + i * 16 + lg * 4 + e;
          float v = acc[i][j][e] + bc;
          const int wv = row >> 6, n = row & 63;
          const int bb = wv >> 6, wi = wv & 63;
          const int hs = (wi >> 3) * 8 + (n >> 3), ws2 = (wi & 7) * 8 + (n & 7);
          const int hh = (hs + 4) & 63, wwp = (ws2 + 4) & 63;
          const size_t orow = (size_t)bb * 4096 + hh * 64 + wwp;
          outf[orow * 512 + col] = resid[orow * 512 + col] + v;
        }
    }
  } else if (EPI == 2) {
#pragma unroll
    for (int j = 0; j < 4; ++j) {
      const int col = n0 + wn * 64 + j * 16 + lr;
      const float bc = bias[col];
#pragma unroll
      for (int i = 0; i < 4; ++i)
#pragma unroll
        for (int e = 0; e < 4; ++e) {
          const int row = m0 + wm * 64 + i * 16 + lg * 4 + e;
          outf[(size_t)row * 512 + col] = acc[i][j][e] + bc + resid[(size_t)row * 512 + col];
        }
    }
  } else {
    // qkv swapped: C row = oc, col = tok. seg uniform per block (m0 mult of 256).
    const int seg = m0 >> 9;
    const float qs = 0.17677669529663687f;
#pragma unroll
    for (int i = 0; i < 4; ++i) {
      const int oc0 = m0 + wm * 64 + i * 16 + lg * 4;
      const float4 bi = *(const float4*)(bias + oc0);
#pragma unroll
      for (int j = 0; j < 4; ++j) {
        const int tok = n0 + wn * 64 + j * 16 + lr;
        if (seg == 0) {
          s16x4 o;
          o[0] = f2bf((acc[i][j][0] + bi.x) * qs);
          o[1] = f2bf((acc[i][j][1] + bi.y) * qs);
          o[2] = f2bf((acc[i][j][2] + bi.z) * qs);
          o[3] = f2bf((acc[i][j][3] + bi.w) * qs);
          *(s16x4*)(outh + (size_t)tok * 512 + oc0) = o;
        } else if (seg == 1) {
          s16x4 o;
          o[0] = f2bf(acc[i][j][0] + bi.x);
          o[1] = f2bf(acc[i][j][1] + bi.y);
          o[2] = f2bf(acc[i][j][2] + bi.z);
          o[3] = f2bf(acc[i][j][3] + bi.w);
          *(s16x4*)(outh + 33554432 + (size_t)tok * 512 + (oc0 - 512)) = o;
        } else {
          const int cc0 = oc0 - 1024;                      // d0 = cc0&31, head = cc0>>5
          short* vbase = outh + 67108864 +
              (size_t)((tok >> 6) * 16 + (cc0 >> 5)) * 2048 + (tok & 63);
          const int d0 = cc0 & 31;
          vbase[(d0 + 0) * 64] = f2bf(acc[i][j][0] + bi.x);
          vbase[(d0 + 1) * 64] = f2bf(acc[i][j][1] + bi.y);
          vbase[(d0 + 2) * 64] = f2bf(acc[i][j][2] + bi.z);
          vbase[(d0 + 3) * 64] = f2bf(acc[i][j][3] + bi.w);
        }
      }
    }
  }
}

// ---------------------------------------------------------------- launch
extern "C" void kernel_launch(void* const* d_in, const int* in_sizes, int n_in,
                              void* d_out, int out_size, void* d_ws, size_t ws_size,
                              hipStream_t stream) {
  (void)in_sizes; (void)n_in; (void)out_size; (void)ws_size;
  const float* x      = (const float*)d_in[0];
  const float* g1     = (const float*)d_in[1];
  const float* b1     = (const float*)d_in[2];
  const float* qkv_w  = (const float*)d_in[3];
  const float* qkv_b  = (const float*)d_in[4];
  const float* proj_w = (const float*)d_in[5];
  const float* proj_b = (const float*)d_in[6];
  const float* rpb    = (const float*)d_in[7];
  const float* g2     = (const float*)d_in[8];
  const float* b2     = (const float*)d_in[9];
  const float* fc1_w  = (const float*)d_in[10];
  const float* fc1_b  = (const float*)d_in[11];
  const float* fc2_w  = (const float*)d_in[12];
  const float* fc2_b  = (const float*)d_in[13];
  float* out = (float*)d_out;
  char* ws = (char*)d_ws;

  short* WQKVT  = (short*)(ws);                 // [1536][512] bf16   1.5MB
  short* WPROJT = (short*)(ws + 1572864);       // [512][512]         0.5MB
  short* WFC1T  = (short*)(ws + 2097152);       // [2048][512]        2MB
  short* WFC2T  = (short*)(ws + 4194304);       // [512][2048]        2MB
  float* X2     = (float*)(ws + 6291456);       // [65536][512] fp32  134MB
  float* BIASF  = (float*)(ws + 6291456);       // 256KB alias (dead before proj)
  short* ATT    = (short*)(ws + 140509184);     // [65536][512] bf16  64MB (X2N reuse)
  short* XW     = (short*)(ws + 207618048);     // [65536][512] bf16  64MB
  short* QB     = (short*)(ws + 274726912);     // Q|K|VT 3x64MB
  short* H1     = XW;                           // [65536][2048] bf16 256MB over XW+QB (dead)
  short* X2N    = ATT;

  prep<<<12544, 256, 0, stream>>>(qkv_w, proj_w, fc1_w, fc2_w, rpb,
                                  WQKVT, WPROJT, WFC1T, WFC2T, BIASF);

  ln_kernel<1><<<16384, 256, 0, stream>>>(x, g1, b1, XW);
  // qkv SWAPPED: A=WQKVT (6 m-tiles), B=XW (512 n-tiles) -> C[oc][tok], packed stores
  gemmBK64<3, 512, 6><<<3072, 512, 0, stream>>>(WQKVT, XW, qkv_b, nullptr, nullptr, QB);
  attn_core<<<4096, 256, 0, stream>>>(QB, QB + 33554432, QB + 67108864, BIASF, ATT);
  // proj: A=ATT (256 m-tiles), BT=WPROJT (4 n-tiles) -> X2 fp32 (window-reverse + x resid)
  gemmBK64<0, 512, 4><<<1024, 512, 0, stream>>>(ATT, WPROJT, proj_b, x, X2, nullptr);
  ln_kernel<0><<<16384, 256, 0, stream>>>(X2, g2, b2, X2N);
  // fc1 swapped: A=W1T (8 m-tiles), B=X2N (512 n-tiles) -> H1[tok][2048]
  gemmBK64<1, 512, 8><<<4096, 512, 0, stream>>>(WFC1T, X2N, fc1_b, nullptr, nullptr, H1);
  // fc2: A=H1 (256 m-tiles), BT=W2T (4 n-tiles) -> out fp32 + bias + X2 resid
  gemmBK64<2, 2048, 4><<<1024, 512, 0, stream>>>(H1, WFC2T, fc2_b, X2, out, nullptr);
}

// Round 22
// 830.133 us; speedup vs baseline: 1.0790x; 1.0192x over previous
//
#include <hip/hip_runtime.h>
#include <hip/hip_bf16.h>

using f32x4  = __attribute__((ext_vector_type(4))) float;
using bf16x8 = __attribute__((ext_vector_type(8))) short;
using short8 = __attribute__((ext_vector_type(8))) short;
using s16x4  = __attribute__((ext_vector_type(4))) short;

#define DEVINL __device__ __forceinline__

DEVINL short f2bf(float f) {
  unsigned u = __builtin_bit_cast(unsigned, f);
  u += 0x7fffu + ((u >> 16) & 1u);          // RNE
  return (short)(u >> 16);
}

// tanh-approx GELU in sigmoid form: 0.5v(1+tanh(u)) == v/(1+exp(-2u))
DEVINL float gelu_fast(float v) {
  float t = __expf(-1.5957691216057308f * (v + 0.044715f * v * v * v));
  return v * __builtin_amdgcn_rcpf(1.0f + t);
}

#define GLDS16(g, l) __builtin_amdgcn_global_load_lds( \
    (const __attribute__((address_space(1))) void*)(g), \
    (__attribute__((address_space(3))) void*)(l), 16, 0, 0)

// ---------------------------------------------------------------- fused prep
__global__ __launch_bounds__(256)
void prep(const float* __restrict__ qkv_w, const float* __restrict__ proj_w,
          const float* __restrict__ fc1_w, const float* __restrict__ fc2_w,
          const float* __restrict__ rpb,
          short* __restrict__ WQKVT, short* __restrict__ WPROJT,
          short* __restrict__ WFC1T, short* __restrict__ WFC2T,
          float* __restrict__ BIASF) {
  const int b = blockIdx.x, t = threadIdx.x;
  if (b < 3072) {                 // WQKVT [1536][512] <- qkv_w [512][1536]
    int idx = b * 256 + t; int c = idx / 512, r = idx % 512;
    WQKVT[idx] = f2bf(qkv_w[(size_t)r * 1536 + c]);
  } else if (b < 4096) {          // WPROJT [512][512]
    int idx = (b - 3072) * 256 + t; int c = idx / 512, r = idx % 512;
    WPROJT[idx] = f2bf(proj_w[(size_t)r * 512 + c]);
  } else if (b < 8192) {          // WFC1T [2048][512]
    int idx = (b - 4096) * 256 + t; int c = idx / 512, r = idx % 512;
    WFC1T[idx] = f2bf(fc1_w[(size_t)r * 2048 + c]);
  } else if (b < 12288) {         // WFC2T [512][2048]
    int idx = (b - 8192) * 256 + t; int c = idx / 2048, r = idx % 2048;
    WFC2T[idx] = f2bf(fc2_w[(size_t)r * 512 + c]);
  } else {                        // BIASF[head][n][m]
    int idx = (b - 12288) * 256 + t;
    int head = idx >> 12, n = (idx >> 6) & 63, m = idx & 63;
    int i1 = n >> 3, j1 = n & 7, i2 = m >> 3, j2 = m & 7;
    BIASF[idx] = rpb[((i1 - i2 + 7) * 15 + (j1 - j2 + 7)) * 16 + head];
  }
}

// ---------------------------------------------------------------- LayerNorm
template<int REMAP>
__global__ __launch_bounds__(256)
void ln_kernel(const float* __restrict__ X, const float* __restrict__ gamma,
               const float* __restrict__ beta, short* __restrict__ OUT) {
  const int lane = threadIdx.x & 63;
  const int wid  = threadIdx.x >> 6;
  const int t    = blockIdx.x * 4 + wid;
  const float* xp = X + (size_t)t * 512 + lane * 8;
  float4 a = *(const float4*)xp;
  float4 b = *(const float4*)(xp + 4);
  float s = a.x + a.y + a.z + a.w + b.x + b.y + b.z + b.w;
  float q = a.x*a.x + a.y*a.y + a.z*a.z + a.w*a.w
          + b.x*b.x + b.y*b.y + b.z*b.z + b.w*b.w;
#pragma unroll
  for (int d = 1; d < 64; d <<= 1) { s += __shfl_xor(s, d); q += __shfl_xor(q, d); }
  float mean = s * (1.0f / 512.0f);
  float var  = q * (1.0f / 512.0f) - mean * mean;
  float rstd = rsqrtf(var + 1e-5f);
  float4 g0 = *(const float4*)(gamma + lane * 8);
  float4 g1 = *(const float4*)(gamma + lane * 8 + 4);
  float4 b0 = *(const float4*)(beta + lane * 8);
  float4 b1 = *(const float4*)(beta + lane * 8 + 4);
  short8 o;
  o[0] = f2bf((a.x - mean) * rstd * g0.x + b0.x);
  o[1] = f2bf((a.y - mean) * rstd * g0.y + b0.y);
  o[2] = f2bf((a.z - mean) * rstd * g0.z + b0.z);
  o[3] = f2bf((a.w - mean) * rstd * g0.w + b0.w);
  o[4] = f2bf((b.x - mean) * rstd * g1.x + b1.x);
  o[5] = f2bf((b.y - mean) * rstd * g1.y + b1.y);
  o[6] = f2bf((b.z - mean) * rstd * g1.z + b1.z);
  o[7] = f2bf((b.w - mean) * rstd * g1.w + b1.w);
  size_t orow;
  if (REMAP) {
    int bb = t >> 12, l = t & 4095, hh = l >> 6, ww = l & 63;
    int hs = (hh + 60) & 63, ws2 = (ww + 60) & 63;   // (coord - 4) mod 64
    orow = (size_t)(bb * 64 + (hs >> 3) * 8 + (ws2 >> 3)) * 64 + (hs & 7) * 8 + (ws2 & 7);
  } else {
    orow = (size_t)t;
  }
  *(short8*)(OUT + orow * 512 + lane * 8) = o;
}

// ---------------------------------------------------------------- attention core
__global__ __launch_bounds__(256)
void attn_core(const short* __restrict__ Q, const short* __restrict__ Kb,
               const short* __restrict__ VT, const float* __restrict__ BIASF,
               short* __restrict__ AOUT) {
  __shared__ short P[4][4096];
  const int tid = threadIdx.x, lane = tid & 63, wid = tid >> 6;
  const int lr = lane & 15, lg = lane >> 4;
  const int gw = blockIdx.x * 4 + wid;
  const int win = gw >> 4, head = gw & 15;
  const int wimg = win & 63, wh = wimg >> 3, ww = wimg & 7;
  const size_t qbase = (size_t)win * 64 * 512 + head * 32;
  short* Pb = P[wid];

  bf16x8 aq[4], bk[4];
#pragma unroll
  for (int tm = 0; tm < 4; ++tm) aq[tm] = *(const bf16x8*)(Q  + qbase + (size_t)(tm * 16 + lr) * 512 + lg * 8);
#pragma unroll
  for (int tn = 0; tn < 4; ++tn) bk[tn] = *(const bf16x8*)(Kb + qbase + (size_t)(tn * 16 + lr) * 512 + lg * 8);
  f32x4 sa[4][4] = {};
#pragma unroll
  for (int tm = 0; tm < 4; ++tm)
#pragma unroll
    for (int tn = 0; tn < 4; ++tn)
      sa[tm][tn] = __builtin_amdgcn_mfma_f32_16x16x32_bf16(aq[tm], bk[tn], sa[tm][tn], 0, 0, 0);

  const float* bias_h = BIASF + head * 4096;
  float inv[4][4];
#pragma unroll
  for (int tm = 0; tm < 4; ++tm) {
#pragma unroll
    for (int e = 0; e < 4; ++e) {
      const int n = tm * 16 + lg * 4 + e;
      const int i1 = n >> 3, j1 = n & 7;
      const int rh1 = (wh == 7) ? 1 + (i1 >> 2) : 0;
      const int rw1 = (ww == 7) ? 1 + (j1 >> 2) : 0;
      float v[4];
      float mx = -3.0e38f;
#pragma unroll
      for (int tn = 0; tn < 4; ++tn) {
        const int m = tn * 16 + lr;
        const int mi = (m >> 3), mj = m & 7;
        const int rh2 = (wh == 7) ? 1 + (mi >> 2) : 0;
        const int rw2 = (ww == 7) ? 1 + (mj >> 2) : 0;
        float val = sa[tm][tn][e] + bias_h[n * 64 + m]
                  + ((rh1 != rh2 || rw1 != rw2) ? -100.0f : 0.0f);
        v[tn] = val;
        mx = fmaxf(mx, val);
      }
#pragma unroll
      for (int d = 1; d < 16; d <<= 1) mx = fmaxf(mx, __shfl_xor(mx, d));
      float sum = 0.f;
#pragma unroll
      for (int tn = 0; tn < 4; ++tn) { v[tn] = __expf(v[tn] - mx); sum += v[tn]; }
#pragma unroll
      for (int d = 1; d < 16; d <<= 1) sum += __shfl_xor(sum, d);
      inv[tm][e] = 1.0f / sum;
      const int sw = (n & 7) << 3;
#pragma unroll
      for (int tn = 0; tn < 4; ++tn) Pb[n * 64 + ((tn * 16 + lr) ^ sw)] = f2bf(v[tn]);
    }
  }
  __syncthreads();

  f32x4 oa[4][2] = {};
  const short* vt = VT + (size_t)win * 32768 + head * 2048;
#pragma unroll
  for (int ks = 0; ks < 2; ++ks) {
    bf16x8 pa[4], bv[2];
#pragma unroll
    for (int tm = 0; tm < 4; ++tm) {
      const int r = tm * 16 + lr;
      pa[tm] = *(const bf16x8*)(Pb + r * 64 + ((ks * 32 + lg * 8) ^ ((r & 7) << 3)));
    }
#pragma unroll
    for (int t2 = 0; t2 < 2; ++t2) bv[t2] = *(const bf16x8*)(vt + (t2 * 16 + lr) * 64 + ks * 32 + lg * 8);
#pragma unroll
    for (int tm = 0; tm < 4; ++tm)
#pragma unroll
      for (int t2 = 0; t2 < 2; ++t2)
        oa[tm][t2] = __builtin_amdgcn_mfma_f32_16x16x32_bf16(pa[tm], bv[t2], oa[tm][t2], 0, 0, 0);
  }
#pragma unroll
  for (int tm = 0; tm < 4; ++tm)
#pragma unroll
    for (int t2 = 0; t2 < 2; ++t2)
#pragma unroll
      for (int e = 0; e < 4; ++e) {
        const int n = tm * 16 + lg * 4 + e;
        AOUT[((size_t)win * 64 + n) * 512 + head * 32 + t2 * 16 + lr] = f2bf(oa[tm][t2][e] * inv[tm][e]);
      }
}

// ---------------------------------------------------------------- 256x128 GEMM, BK=64 (R17 structure)
// EPI 0 (proj): C[tok][out] -> X2 fp32 window-reversed + x residual + bias
// EPI 1 (fc1, swapped): C[h][tok] -> H1[tok][2048] bf16 gelu, packed s16x4
// EPI 2 (fc2): C[tok][out] -> out fp32 = acc + bias + X2 residual
// EPI 3 (qkv, swapped): LDS-coalesced stores — Q/K as [tok][oc] 64B bursts,
//                       V^T as [d][tok] 128B bursts (sector-exact, no amp).
template<int EPI, int K, int NX>
__global__ __launch_bounds__(512, 1)
void gemmBK64(const short* __restrict__ Aa, const short* __restrict__ Bb,
              const float* __restrict__ bias, const float* __restrict__ resid,
              float* __restrict__ outf, short* __restrict__ outh) {
  constexpr int NT = K / 64;
  __shared__ short L[24576];   // A bytes [0,32768), B bytes [32768,49152)
  const int tid = threadIdx.x;
  const int lane = tid & 63, wid = tid >> 6;
  const int lr = lane & 15, lg = lane >> 4;
  const int wm = wid >> 1, wn = wid & 1;

  // XCD-aware bijective swizzle (all grids are multiples of 8)
  const int nwg = gridDim.x;
  const int id = blockIdx.x;
  const int id2 = (id & 7) * (nwg >> 3) + (id >> 3);
  const bool swapped = (EPI == 1 || EPI == 3);
  const int mt    = swapped ? (id2 % NX) : (id2 / NX);
  const int ntile = swapped ? (id2 / NX) : (id2 % NX);
  const int m0 = mt * 256, n0 = ntile * 128;

  // staging geometry: instr c -> row c*64 + rr, phys slot tid&7
  const int rr = tid >> 3;                                   // 0..63
  const int ss = ((tid & 7) ^ (rr & 7)) * 8;                 // swizzled source col (elems)
  const short* pA = Aa + (size_t)(m0 + rr) * K + ss;
  const short* pB = Bb + (size_t)(n0 + rr) * K + ss;
  char* Ld = (char*)L + tid * 16;

  // frag read bases (slot = (kk*4+lg)^(lr&7))
  const int xr = lr & 7;
  const char* rA0 = (char*)L + (wm * 64 + lr) * 128 + ((lg ^ xr) << 4);
  const char* rA1 = (char*)L + (wm * 64 + lr) * 128 + (((4 + lg) ^ xr) << 4);
  const char* rB0 = (char*)L + 32768 + (wn * 64 + lr) * 128 + ((lg ^ xr) << 4);
  const char* rB1 = (char*)L + 32768 + (wn * 64 + lr) * 128 + (((4 + lg) ^ xr) << 4);

  f32x4 acc[4][4] = {};
  for (int kt = 0; kt < NT; ++kt) {
    const int ko = kt * 64;
    GLDS16(pA + ko,                    Ld);
    GLDS16(pA + ko + (size_t)64  * K,  Ld + 8192);
    GLDS16(pA + ko + (size_t)128 * K,  Ld + 16384);
    GLDS16(pA + ko + (size_t)192 * K,  Ld + 24576);
    GLDS16(pB + ko,                    Ld + 32768);
    GLDS16(pB + ko + (size_t)64  * K,  Ld + 40960);
    __syncthreads();
    bf16x8 a[4], b[4];
#pragma unroll
    for (int i = 0; i < 4; ++i) a[i] = *(const bf16x8*)(rA0 + i * 2048);
#pragma unroll
    for (int j = 0; j < 4; ++j) b[j] = *(const bf16x8*)(rB0 + j * 2048);
#pragma unroll
    for (int i = 0; i < 4; ++i)
#pragma unroll
      for (int j = 0; j < 4; ++j)
        acc[i][j] = __builtin_amdgcn_mfma_f32_16x16x32_bf16(a[i], b[j], acc[i][j], 0, 0, 0);
#pragma unroll
    for (int i = 0; i < 4; ++i) a[i] = *(const bf16x8*)(rA1 + i * 2048);
#pragma unroll
    for (int j = 0; j < 4; ++j) b[j] = *(const bf16x8*)(rB1 + j * 2048);
#pragma unroll
    for (int i = 0; i < 4; ++i)
#pragma unroll
      for (int j = 0; j < 4; ++j)
        acc[i][j] = __builtin_amdgcn_mfma_f32_16x16x32_bf16(a[i], b[j], acc[i][j], 0, 0, 0);
    __syncthreads();
  }

  // ---- epilogue
  if (EPI == 1) {
#pragma unroll
    for (int i = 0; i < 4; ++i) {
      const int h0 = m0 + wm * 64 + i * 16 + lg * 4;
      const float4 bi = *(const float4*)(bias + h0);
#pragma unroll
      for (int j = 0; j < 4; ++j) {
        const int tok = n0 + wn * 64 + j * 16 + lr;
        s16x4 o;
        o[0] = f2bf(gelu_fast(acc[i][j][0] + bi.x));
        o[1] = f2bf(gelu_fast(acc[i][j][1] + bi.y));
        o[2] = f2bf(gelu_fast(acc[i][j][2] + bi.z));
        o[3] = f2bf(gelu_fast(acc[i][j][3] + bi.w));
        *(s16x4*)(outh + (size_t)tok * 2048 + h0) = o;
      }
    }
  } else if (EPI == 0) {
#pragma unroll
    for (int j = 0; j < 4; ++j) {
      const int col = n0 + wn * 64 + j * 16 + lr;
      const float bc = bias[col];
#pragma unroll
      for (int i = 0; i < 4; ++i)
#pragma unroll
        for (int e = 0; e < 4; ++e) {
          const int row = m0 + wm * 64 + i * 16 + lg * 4 + e;
          float v = acc[i][j][e] + bc;
          const int wv = row >> 6, n = row & 63;
          const int bb = wv >> 6, wi = wv & 63;
          const int hs = (wi >> 3) * 8 + (n >> 3), ws2 = (wi & 7) * 8 + (n & 7);
          const int hh = (hs + 4) & 63, wwp = (ws2 + 4) & 63;
          const size_t orow = (size_t)bb * 4096 + hh * 64 + wwp;
          outf[orow * 512 + col] = resid[orow * 512 + col] + v;
        }
    }
  } else if (EPI == 2) {
#pragma unroll
    for (int j = 0; j < 4; ++j) {
      const int col = n0 + wn * 64 + j * 16 + lr;
      const float bc = bias[col];
#pragma unroll
      for (int i = 0; i < 4; ++i)
#pragma unroll
        for (int e = 0; e < 4; ++e) {
          const int row = m0 + wm * 64 + i * 16 + lg * 4 + e;
          outf[(size_t)row * 512 + col] = acc[i][j][e] + bc + resid[(size_t)row * 512 + col];
        }
    }
  } else {
    // qkv swapped, LDS-coalesced: wave-private scratch (DS ops in-order per
    // wave; loop's final __syncthreads fences cross-wave main-loop reads).
    const int seg = m0 >> 9;
    const float qs = (seg == 0) ? 0.17677669529663687f : 1.0f;
    char* W = (char*)L + wid * 4352;
    const int tok0w = n0 + wn * 64;
    const int oc0w  = m0 + wm * 64;
#pragma unroll
    for (int h = 0; h < 2; ++h) {
      // write phase: oc half h (i = 2h, 2h+1)
#pragma unroll
      for (int ii = 0; ii < 2; ++ii) {
        const int i = 2 * h + ii;
        const float4 bi = *(const float4*)(bias + oc0w + i * 16 + lg * 4);
        const float bb[4] = {bi.x, bi.y, bi.z, bi.w};
#pragma unroll
        for (int j = 0; j < 4; ++j)
#pragma unroll
          for (int e = 0; e < 4; ++e) {
            const short hv = f2bf((acc[i][j][e] + bb[e]) * qs);
            if (seg == 2)
              *(short*)(W + (ii * 16 + lg * 4 + e) * 132 + (j * 16 + lr) * 2) = hv;   // [d][tok+pad]
            else
              *(short*)(W + (j * 16 + lr) * 68 + (ii * 16 + lg * 4 + e) * 2) = hv;    // [tok][oc+pad]
          }
      }
      // read + sector-exact store phase
      if (seg == 2) {
#pragma unroll
        for (int p = 0; p < 4; ++p) {
          const int dl = p * 8 + (lane >> 3);          // 0..31
          const bf16x8 v = *(const bf16x8*)(W + dl * 132 + (lane & 7) * 16);
          const int dglob = (oc0w - 1024) + h * 32 + dl;
          *(bf16x8*)(outh + 67108864 +
                     (size_t)((tok0w >> 6) * 16 + (dglob >> 5)) * 2048 +
                     (dglob & 31) * 64 + (lane & 7) * 8) = v;   // 8 lanes = 128B row
        }
      } else {
#pragma unroll
        for (int p = 0; p < 4; ++p) {
          const int tokl = p * 16 + (lane >> 2);       // 0..63
          const bf16x8 v = *(const bf16x8*)(W + tokl * 68 + (lane & 3) * 16);
          short* dst = (seg == 0) ? outh : (outh + 33554432 - 512);
          *(bf16x8*)(dst + (size_t)(tok0w + tokl) * 512 + oc0w + h * 32 + (lane & 3) * 8) = v;
        }
      }
    }
  }
}

// ---------------------------------------------------------------- launch
extern "C" void kernel_launch(void* const* d_in, const int* in_sizes, int n_in,
                              void* d_out, int out_size, void* d_ws, size_t ws_size,
                              hipStream_t stream) {
  (void)in_sizes; (void)n_in; (void)out_size; (void)ws_size;
  const float* x      = (const float*)d_in[0];
  const float* g1     = (const float*)d_in[1];
  const float* b1     = (const float*)d_in[2];
  const float* qkv_w  = (const float*)d_in[3];
  const float* qkv_b  = (const float*)d_in[4];
  const float* proj_w = (const float*)d_in[5];
  const float* proj_b = (const float*)d_in[6];
  const float* rpb    = (const float*)d_in[7];
  const float* g2     = (const float*)d_in[8];
  const float* b2     = (const float*)d_in[9];
  const float* fc1_w  = (const float*)d_in[10];
  const float* fc1_b  = (const float*)d_in[11];
  const float* fc2_w  = (const float*)d_in[12];
  const float* fc2_b  = (const float*)d_in[13];
  float* out = (float*)d_out;
  char* ws = (char*)d_ws;

  short* WQKVT  = (short*)(ws);                 // [1536][512] bf16   1.5MB
  short* WPROJT = (short*)(ws + 1572864);       // [512][512]         0.5MB
  short* WFC1T  = (short*)(ws + 2097152);       // [2048][512]        2MB
  short* WFC2T  = (short*)(ws + 4194304);       // [512][2048]        2MB
  float* X2     = (float*)(ws + 6291456);       // [65536][512] fp32  134MB
  float* BIASF  = (float*)(ws + 6291456);       // 256KB alias (dead before proj)
  short* ATT    = (short*)(ws + 140509184);     // [65536][512] bf16  64MB (X2N reuse)
  short* XW     = (short*)(ws + 207618048);     // [65536][512] bf16  64MB
  short* QB     = (short*)(ws + 274726912);     // Q|K|VT 3x64MB
  short* H1     = XW;                           // [65536][2048] bf16 256MB over XW+QB (dead)
  short* X2N    = ATT;

  prep<<<12544, 256, 0, stream>>>(qkv_w, proj_w, fc1_w, fc2_w, rpb,
                                  WQKVT, WPROJT, WFC1T, WFC2T, BIASF);

  ln_kernel<1><<<16384, 256, 0, stream>>>(x, g1, b1, XW);
  // qkv SWAPPED: A=WQKVT (6 m-tiles), B=XW (512 n-tiles) -> C[oc][tok], LDS-coalesced stores
  gemmBK64<3, 512, 6><<<3072, 512, 0, stream>>>(WQKVT, XW, qkv_b, nullptr, nullptr, QB);
  attn_core<<<4096, 256, 0, stream>>>(QB, QB + 33554432, QB + 67108864, BIASF, ATT);
  // proj: A=ATT (256 m-tiles), BT=WPROJT (4 n-tiles) -> X2 fp32 (window-reverse + x resid)
  gemmBK64<0, 512, 4><<<1024, 512, 0, stream>>>(ATT, WPROJT, proj_b, x, X2, nullptr);
  ln_kernel<0><<<16384, 256, 0, stream>>>(X2, g2, b2, X2N);
  // fc1 swapped: A=W1T (8 m-tiles), B=X2N (512 n-tiles) -> H1[tok][2048]
  gemmBK64<1, 512, 8><<<4096, 512, 0, stream>>>(WFC1T, X2N, fc1_b, nullptr, nullptr, H1);
  // fc2: A=H1 (256 m-tiles), BT=W2T (4 n-tiles) -> out fp32 + bias + X2 resid
  gemmBK64<2, 2048, 4><<<1024, 512, 0, stream>>>(H1, WFC2T, fc2_b, X2, out, nullptr);
}

// Round 23
// 817.171 us; speedup vs baseline: 1.0962x; 1.0159x over previous
//
#include <hip/hip_runtime.h>
#include <hip/hip_bf16.h>

using f32x4  = __attribute__((ext_vector_type(4))) float;
using bf16x8 = __attribute__((ext_vector_type(8))) short;
using short8 = __attribute__((ext_vector_type(8))) short;
using s16x4  = __attribute__((ext_vector_type(4))) short;

#define DEVINL __device__ __forceinline__

DEVINL short f2bf(float f) {
  unsigned u = __builtin_bit_cast(unsigned, f);
  u += 0x7fffu + ((u >> 16) & 1u);          // RNE
  return (short)(u >> 16);
}

// tanh-approx GELU in sigmoid form: 0.5v(1+tanh(u)) == v/(1+exp(-2u))
DEVINL float gelu_fast(float v) {
  float t = __expf(-1.5957691216057308f * (v + 0.044715f * v * v * v));
  return v * __builtin_amdgcn_rcpf(1.0f + t);
}

#define GLDS16(g, l) __builtin_amdgcn_global_load_lds( \
    (const __attribute__((address_space(1))) void*)(g), \
    (__attribute__((address_space(3))) void*)(l), 16, 0, 0)

// ---------------------------------------------------------------- fused prep (LDS-tiled transposes)
// R22's prep read fp32 column-strided (6KB stride -> 16x sector amplification,
// ~400MB effective). Tiled: coalesced 256B reads -> LDS (64x65 pad) ->
// conflict-free column reads -> coalesced 128B bf16 writes.
__global__ __launch_bounds__(256)
void prep(const float* __restrict__ qkv_w, const float* __restrict__ proj_w,
          const float* __restrict__ fc1_w, const float* __restrict__ fc2_w,
          const float* __restrict__ rpb,
          short* __restrict__ WQKVT, short* __restrict__ WPROJT,
          short* __restrict__ WFC1T, short* __restrict__ WFC2T,
          float* __restrict__ BIASF) {
  __shared__ float tile[64][65];
  const int b = blockIdx.x, t = threadIdx.x;
  const float* src; short* dst; int R, C, boff;
  if (b < 192)      { src = qkv_w;  dst = WQKVT;  R = 512;  C = 1536; boff = b; }
  else if (b < 256) { src = proj_w; dst = WPROJT; R = 512;  C = 512;  boff = b - 192; }
  else if (b < 512) { src = fc1_w;  dst = WFC1T;  R = 512;  C = 2048; boff = b - 256; }
  else if (b < 768) { src = fc2_w;  dst = WFC2T;  R = 2048; C = 512;  boff = b - 512; }
  else {
    int idx = (b - 768) * 256 + t;   // BIASF[head][n][m], 65536 elems
    int head = idx >> 12, n = (idx >> 6) & 63, m = idx & 63;
    int i1 = n >> 3, j1 = n & 7, i2 = m >> 3, j2 = m & 7;
    BIASF[idx] = rpb[((i1 - i2 + 7) * 15 + (j1 - j2 + 7)) * 16 + head];
    return;
  }
  const int tc = C >> 6;
  const int r0 = (boff / tc) * 64, c0 = (boff % tc) * 64;
  const int row4 = t >> 6, col = t & 63;
#pragma unroll
  for (int rep = 0; rep < 16; ++rep) {
    const int row = rep * 4 + row4;
    tile[row][col] = src[(size_t)(r0 + row) * C + c0 + col];
  }
  __syncthreads();
#pragma unroll
  for (int rep = 0; rep < 16; ++rep) {
    const int crow = rep * 4 + row4;
    dst[(size_t)(c0 + crow) * R + r0 + col] = f2bf(tile[col][crow]);
  }
}

// ---------------------------------------------------------------- LayerNorm
template<int REMAP>
__global__ __launch_bounds__(256)
void ln_kernel(const float* __restrict__ X, const float* __restrict__ gamma,
               const float* __restrict__ beta, short* __restrict__ OUT) {
  const int lane = threadIdx.x & 63;
  const int wid  = threadIdx.x >> 6;
  const int t    = blockIdx.x * 4 + wid;
  const float* xp = X + (size_t)t * 512 + lane * 8;
  float4 a = *(const float4*)xp;
  float4 b = *(const float4*)(xp + 4);
  float s = a.x + a.y + a.z + a.w + b.x + b.y + b.z + b.w;
  float q = a.x*a.x + a.y*a.y + a.z*a.z + a.w*a.w
          + b.x*b.x + b.y*b.y + b.z*b.z + b.w*b.w;
#pragma unroll
  for (int d = 1; d < 64; d <<= 1) { s += __shfl_xor(s, d); q += __shfl_xor(q, d); }
  float mean = s * (1.0f / 512.0f);
  float var  = q * (1.0f / 512.0f) - mean * mean;
  float rstd = rsqrtf(var + 1e-5f);
  float4 g0 = *(const float4*)(gamma + lane * 8);
  float4 g1 = *(const float4*)(gamma + lane * 8 + 4);
  float4 b0 = *(const float4*)(beta + lane * 8);
  float4 b1 = *(const float4*)(beta + lane * 8 + 4);
  short8 o;
  o[0] = f2bf((a.x - mean) * rstd * g0.x + b0.x);
  o[1] = f2bf((a.y - mean) * rstd * g0.y + b0.y);
  o[2] = f2bf((a.z - mean) * rstd * g0.z + b0.z);
  o[3] = f2bf((a.w - mean) * rstd * g0.w + b0.w);
  o[4] = f2bf((b.x - mean) * rstd * g1.x + b1.x);
  o[5] = f2bf((b.y - mean) * rstd * g1.y + b1.y);
  o[6] = f2bf((b.z - mean) * rstd * g1.z + b1.z);
  o[7] = f2bf((b.w - mean) * rstd * g1.w + b1.w);
  size_t orow;
  if (REMAP) {
    int bb = t >> 12, l = t & 4095, hh = l >> 6, ww = l & 63;
    int hs = (hh + 60) & 63, ws2 = (ww + 60) & 63;   // (coord - 4) mod 64
    orow = (size_t)(bb * 64 + (hs >> 3) * 8 + (ws2 >> 3)) * 64 + (hs & 7) * 8 + (ws2 & 7);
  } else {
    orow = (size_t)t;
  }
  *(short8*)(OUT + orow * 512 + lane * 8) = o;
}

// ---------------------------------------------------------------- attention core
__global__ __launch_bounds__(256)
void attn_core(const short* __restrict__ Q, const short* __restrict__ Kb,
               const short* __restrict__ VT, const float* __restrict__ BIASF,
               short* __restrict__ AOUT) {
  __shared__ short P[4][4096];
  const int tid = threadIdx.x, lane = tid & 63, wid = tid >> 6;
  const int lr = lane & 15, lg = lane >> 4;
  const int gw = blockIdx.x * 4 + wid;
  const int win = gw >> 4, head = gw & 15;
  const int wimg = win & 63, wh = wimg >> 3, ww = wimg & 7;
  const size_t qbase = (size_t)win * 64 * 512 + head * 32;
  short* Pb = P[wid];

  bf16x8 aq[4], bk[4];
#pragma unroll
  for (int tm = 0; tm < 4; ++tm) aq[tm] = *(const bf16x8*)(Q  + qbase + (size_t)(tm * 16 + lr) * 512 + lg * 8);
#pragma unroll
  for (int tn = 0; tn < 4; ++tn) bk[tn] = *(const bf16x8*)(Kb + qbase + (size_t)(tn * 16 + lr) * 512 + lg * 8);
  f32x4 sa[4][4] = {};
#pragma unroll
  for (int tm = 0; tm < 4; ++tm)
#pragma unroll
    for (int tn = 0; tn < 4; ++tn)
      sa[tm][tn] = __builtin_amdgcn_mfma_f32_16x16x32_bf16(aq[tm], bk[tn], sa[tm][tn], 0, 0, 0);

  const float* bias_h = BIASF + head * 4096;
  float inv[4][4];
#pragma unroll
  for (int tm = 0; tm < 4; ++tm) {
#pragma unroll
    for (int e = 0; e < 4; ++e) {
      const int n = tm * 16 + lg * 4 + e;
      const int i1 = n >> 3, j1 = n & 7;
      const int rh1 = (wh == 7) ? 1 + (i1 >> 2) : 0;
      const int rw1 = (ww == 7) ? 1 + (j1 >> 2) : 0;
      float v[4];
      float mx = -3.0e38f;
#pragma unroll
      for (int tn = 0; tn < 4; ++tn) {
        const int m = tn * 16 + lr;
        const int mi = (m >> 3), mj = m & 7;
        const int rh2 = (wh == 7) ? 1 + (mi >> 2) : 0;
        const int rw2 = (ww == 7) ? 1 + (mj >> 2) : 0;
        float val = sa[tm][tn][e] + bias_h[n * 64 + m]
                  + ((rh1 != rh2 || rw1 != rw2) ? -100.0f : 0.0f);
        v[tn] = val;
        mx = fmaxf(mx, val);
      }
#pragma unroll
      for (int d = 1; d < 16; d <<= 1) mx = fmaxf(mx, __shfl_xor(mx, d));
      float sum = 0.f;
#pragma unroll
      for (int tn = 0; tn < 4; ++tn) { v[tn] = __expf(v[tn] - mx); sum += v[tn]; }
#pragma unroll
      for (int d = 1; d < 16; d <<= 1) sum += __shfl_xor(sum, d);
      inv[tm][e] = 1.0f / sum;
      const int sw = (n & 7) << 3;
#pragma unroll
      for (int tn = 0; tn < 4; ++tn) Pb[n * 64 + ((tn * 16 + lr) ^ sw)] = f2bf(v[tn]);
    }
  }
  __syncthreads();

  f32x4 oa[4][2] = {};
  const short* vt = VT + (size_t)win * 32768 + head * 2048;
#pragma unroll
  for (int ks = 0; ks < 2; ++ks) {
    bf16x8 pa[4], bv[2];
#pragma unroll
    for (int tm = 0; tm < 4; ++tm) {
      const int r = tm * 16 + lr;
      pa[tm] = *(const bf16x8*)(Pb + r * 64 + ((ks * 32 + lg * 8) ^ ((r & 7) << 3)));
    }
#pragma unroll
    for (int t2 = 0; t2 < 2; ++t2) bv[t2] = *(const bf16x8*)(vt + (t2 * 16 + lr) * 64 + ks * 32 + lg * 8);
#pragma unroll
    for (int tm = 0; tm < 4; ++tm)
#pragma unroll
      for (int t2 = 0; t2 < 2; ++t2)
        oa[tm][t2] = __builtin_amdgcn_mfma_f32_16x16x32_bf16(pa[tm], bv[t2], oa[tm][t2], 0, 0, 0);
  }
#pragma unroll
  for (int tm = 0; tm < 4; ++tm)
#pragma unroll
    for (int t2 = 0; t2 < 2; ++t2)
#pragma unroll
      for (int e = 0; e < 4; ++e) {
        const int n = tm * 16 + lg * 4 + e;
        AOUT[((size_t)win * 64 + n) * 512 + head * 32 + t2 * 16 + lr] = f2bf(oa[tm][t2][e] * inv[tm][e]);
      }
}

// ---------------------------------------------------------------- 256x128 GEMM, BK=64 (R17 structure)
// EPI 0 (proj): C[tok][out] -> X2 fp32 window-reversed + x residual + bias
// EPI 1 (fc1, swapped): C[h][tok] -> H1[tok][2048] bf16 gelu, packed s16x4
// EPI 2 (fc2): C[tok][out] -> out fp32 = acc + bias + X2 residual
// EPI 3 (qkv, swapped): LDS-coalesced stores — Q/K as [tok][oc] 64B bursts,
//                       V^T as [d][tok] 128B bursts (sector-exact, no amp).
template<int EPI, int K, int NX>
__global__ __launch_bounds__(512, 1)
void gemmBK64(const short* __restrict__ Aa, const short* __restrict__ Bb,
              const float* __restrict__ bias, const float* __restrict__ resid,
              float* __restrict__ outf, short* __restrict__ outh) {
  constexpr int NT = K / 64;
  __shared__ short L[24576];   // A bytes [0,32768), B bytes [32768,49152)
  const int tid = threadIdx.x;
  const int lane = tid & 63, wid = tid >> 6;
  const int lr = lane & 15, lg = lane >> 4;
  const int wm = wid >> 1, wn = wid & 1;

  // XCD-aware bijective swizzle (all grids are multiples of 8)
  const int nwg = gridDim.x;
  const int id = blockIdx.x;
  const int id2 = (id & 7) * (nwg >> 3) + (id >> 3);
  const bool swapped = (EPI == 1 || EPI == 3);
  const int mt    = swapped ? (id2 % NX) : (id2 / NX);
  const int ntile = swapped ? (id2 / NX) : (id2 % NX);
  const int m0 = mt * 256, n0 = ntile * 128;

  // staging geometry: instr c -> row c*64 + rr, phys slot tid&7
  const int rr = tid >> 3;                                   // 0..63
  const int ss = ((tid & 7) ^ (rr & 7)) * 8;                 // swizzled source col (elems)
  const short* pA = Aa + (size_t)(m0 + rr) * K + ss;
  const short* pB = Bb + (size_t)(n0 + rr) * K + ss;
  char* Ld = (char*)L + tid * 16;

  // frag read bases (slot = (kk*4+lg)^(lr&7))
  const int xr = lr & 7;
  const char* rA0 = (char*)L + (wm * 64 + lr) * 128 + ((lg ^ xr) << 4);
  const char* rA1 = (char*)L + (wm * 64 + lr) * 128 + (((4 + lg) ^ xr) << 4);
  const char* rB0 = (char*)L + 32768 + (wn * 64 + lr) * 128 + ((lg ^ xr) << 4);
  const char* rB1 = (char*)L + 32768 + (wn * 64 + lr) * 128 + (((4 + lg) ^ xr) << 4);

  f32x4 acc[4][4] = {};
  for (int kt = 0; kt < NT; ++kt) {
    const int ko = kt * 64;
    GLDS16(pA + ko,                    Ld);
    GLDS16(pA + ko + (size_t)64  * K,  Ld + 8192);
    GLDS16(pA + ko + (size_t)128 * K,  Ld + 16384);
    GLDS16(pA + ko + (size_t)192 * K,  Ld + 24576);
    GLDS16(pB + ko,                    Ld + 32768);
    GLDS16(pB + ko + (size_t)64  * K,  Ld + 40960);
    __syncthreads();
    bf16x8 a[4], b[4];
#pragma unroll
    for (int i = 0; i < 4; ++i) a[i] = *(const bf16x8*)(rA0 + i * 2048);
#pragma unroll
    for (int j = 0; j < 4; ++j) b[j] = *(const bf16x8*)(rB0 + j * 2048);
#pragma unroll
    for (int i = 0; i < 4; ++i)
#pragma unroll
      for (int j = 0; j < 4; ++j)
        acc[i][j] = __builtin_amdgcn_mfma_f32_16x16x32_bf16(a[i], b[j], acc[i][j], 0, 0, 0);
#pragma unroll
    for (int i = 0; i < 4; ++i) a[i] = *(const bf16x8*)(rA1 + i * 2048);
#pragma unroll
    for (int j = 0; j < 4; ++j) b[j] = *(const bf16x8*)(rB1 + j * 2048);
#pragma unroll
    for (int i = 0; i < 4; ++i)
#pragma unroll
      for (int j = 0; j < 4; ++j)
        acc[i][j] = __builtin_amdgcn_mfma_f32_16x16x32_bf16(a[i], b[j], acc[i][j], 0, 0, 0);
    __syncthreads();
  }

  // ---- epilogue
  if (EPI == 1) {
#pragma unroll
    for (int i = 0; i < 4; ++i) {
      const int h0 = m0 + wm * 64 + i * 16 + lg * 4;
      const float4 bi = *(const float4*)(bias + h0);
#pragma unroll
      for (int j = 0; j < 4; ++j) {
        const int tok = n0 + wn * 64 + j * 16 + lr;
        s16x4 o;
        o[0] = f2bf(gelu_fast(acc[i][j][0] + bi.x));
        o[1] = f2bf(gelu_fast(acc[i][j][1] + bi.y));
        o[2] = f2bf(gelu_fast(acc[i][j][2] + bi.z));
        o[3] = f2bf(gelu_fast(acc[i][j][3] + bi.w));
        *(s16x4*)(outh + (size_t)tok * 2048 + h0) = o;
      }
    }
  } else if (EPI == 0) {
#pragma unroll
    for (int j = 0; j < 4; ++j) {
      const int col = n0 + wn * 64 + j * 16 + lr;
      const float bc = bias[col];
#pragma unroll
      for (int i = 0; i < 4; ++i)
#pragma unroll
        for (int e = 0; e < 4; ++e) {
          const int row = m0 + wm * 64 + i * 16 + lg * 4 + e;
          float v = acc[i][j][e] + bc;
          const int wv = row >> 6, n = row & 63;
          const int bb = wv >> 6, wi = wv & 63;
          const int hs = (wi >> 3) * 8 + (n >> 3), ws2 = (wi & 7) * 8 + (n & 7);
          const int hh = (hs + 4) & 63, wwp = (ws2 + 4) & 63;
          const size_t orow = (size_t)bb * 4096 + hh * 64 + wwp;
          outf[orow * 512 + col] = resid[orow * 512 + col] + v;
        }
    }
  } else if (EPI == 2) {
#pragma unroll
    for (int j = 0; j < 4; ++j) {
      const int col = n0 + wn * 64 + j * 16 + lr;
      const float bc = bias[col];
#pragma unroll
      for (int i = 0; i < 4; ++i)
#pragma unroll
        for (int e = 0; e < 4; ++e) {
          const int row = m0 + wm * 64 + i * 16 + lg * 4 + e;
          outf[(size_t)row * 512 + col] = acc[i][j][e] + bc + resid[(size_t)row * 512 + col];
        }
    }
  } else {
    // qkv swapped, LDS-coalesced: wave-private scratch (DS ops in-order per
    // wave; loop's final __syncthreads fences cross-wave main-loop reads).
    const int seg = m0 >> 9;
    const float qs = (seg == 0) ? 0.17677669529663687f : 1.0f;
    char* W = (char*)L + wid * 4352;
    const int tok0w = n0 + wn * 64;
    const int oc0w  = m0 + wm * 64;
#pragma unroll
    for (int h = 0; h < 2; ++h) {
      // write phase: oc half h (i = 2h, 2h+1)
#pragma unroll
      for (int ii = 0; ii < 2; ++ii) {
        const int i = 2 * h + ii;
        const float4 bi = *(const float4*)(bias + oc0w + i * 16 + lg * 4);
        const float bb[4] = {bi.x, bi.y, bi.z, bi.w};
#pragma unroll
        for (int j = 0; j < 4; ++j)
#pragma unroll
          for (int e = 0; e < 4; ++e) {
            const short hv = f2bf((acc[i][j][e] + bb[e]) * qs);
            if (seg == 2)
              *(short*)(W + (ii * 16 + lg * 4 + e) * 132 + (j * 16 + lr) * 2) = hv;   // [d][tok+pad]
            else
              *(short*)(W + (j * 16 + lr) * 68 + (ii * 16 + lg * 4 + e) * 2) = hv;    // [tok][oc+pad]
          }
      }
      // read + sector-exact store phase
      if (seg == 2) {
#pragma unroll
        for (int p = 0; p < 4; ++p) {
          const int dl = p * 8 + (lane >> 3);          // 0..31
          const bf16x8 v = *(const bf16x8*)(W + dl * 132 + (lane & 7) * 16);
          const int dglob = (oc0w - 1024) + h * 32 + dl;
          *(bf16x8*)(outh + 67108864 +
                     (size_t)((tok0w >> 6) * 16 + (dglob >> 5)) * 2048 +
                     (dglob & 31) * 64 + (lane & 7) * 8) = v;   // 8 lanes = 128B row
        }
      } else {
#pragma unroll
        for (int p = 0; p < 4; ++p) {
          const int tokl = p * 16 + (lane >> 2);       // 0..63
          const bf16x8 v = *(const bf16x8*)(W + tokl * 68 + (lane & 3) * 16);
          short* dst = (seg == 0) ? outh : (outh + 33554432 - 512);
          *(bf16x8*)(dst + (size_t)(tok0w + tokl) * 512 + oc0w + h * 32 + (lane & 3) * 8) = v;
        }
      }
    }
  }
}

// ---------------------------------------------------------------- launch
extern "C" void kernel_launch(void* const* d_in, const int* in_sizes, int n_in,
                              void* d_out, int out_size, void* d_ws, size_t ws_size,
                              hipStream_t stream) {
  (void)in_sizes; (void)n_in; (void)out_size; (void)ws_size;
  const float* x      = (const float*)d_in[0];
  const float* g1     = (const float*)d_in[1];
  const float* b1     = (const float*)d_in[2];
  const float* qkv_w  = (const float*)d_in[3];
  const float* qkv_b  = (const float*)d_in[4];
  const float* proj_w = (const float*)d_in[5];
  const float* proj_b = (const float*)d_in[6];
  const float* rpb    = (const float*)d_in[7];
  const float* g2     = (const float*)d_in[8];
  const float* b2     = (const float*)d_in[9];
  const float* fc1_w  = (const float*)d_in[10];
  const float* fc1_b  = (const float*)d_in[11];
  const float* fc2_w  = (const float*)d_in[12];
  const float* fc2_b  = (const float*)d_in[13];
  float* out = (float*)d_out;
  char* ws = (char*)d_ws;

  short* WQKVT  = (short*)(ws);                 // [1536][512] bf16   1.5MB
  short* WPROJT = (short*)(ws + 1572864);       // [512][512]         0.5MB
  short* WFC1T  = (short*)(ws + 2097152);       // [2048][512]        2MB
  short* WFC2T  = (short*)(ws + 4194304);       // [512][2048]        2MB
  float* X2     = (float*)(ws + 6291456);       // [65536][512] fp32  134MB
  float* BIASF  = (float*)(ws + 6291456);       // 256KB alias (dead before proj)
  short* ATT    = (short*)(ws + 140509184);     // [65536][512] bf16  64MB (X2N reuse)
  short* XW     = (short*)(ws + 207618048);     // [65536][512] bf16  64MB
  short* QB     = (short*)(ws + 274726912);     // Q|K|VT 3x64MB
  short* H1     = XW;                           // [65536][2048] bf16 256MB over XW+QB (dead)
  short* X2N    = ATT;

  prep<<<1024, 256, 0, stream>>>(qkv_w, proj_w, fc1_w, fc2_w, rpb,
                                 WQKVT, WPROJT, WFC1T, WFC2T, BIASF);

  ln_kernel<1><<<16384, 256, 0, stream>>>(x, g1, b1, XW);
  // qkv SWAPPED: A=WQKVT (6 m-tiles), B=XW (512 n-tiles) -> C[oc][tok], LDS-coalesced stores
  gemmBK64<3, 512, 6><<<3072, 512, 0, stream>>>(WQKVT, XW, qkv_b, nullptr, nullptr, QB);
  attn_core<<<4096, 256, 0, stream>>>(QB, QB + 33554432, QB + 67108864, BIASF, ATT);
  // proj: A=ATT (256 m-tiles), BT=WPROJT (4 n-tiles) -> X2 fp32 (window-reverse + x resid)
  gemmBK64<0, 512, 4><<<1024, 512, 0, stream>>>(ATT, WPROJT, proj_b, x, X2, nullptr);
  ln_kernel<0><<<16384, 256, 0, stream>>>(X2, g2, b2, X2N);
  // fc1 swapped: A=W1T (8 m-tiles), B=X2N (512 n-tiles) -> H1[tok][2048]
  gemmBK64<1, 512, 8><<<4096, 512, 0, stream>>>(WFC1T, X2N, fc1_b, nullptr, nullptr, H1);
  // fc2: A=H1 (256 m-tiles), BT=W2T (4 n-tiles) -> out fp32 + bias + X2 resid
  gemmBK64<2, 2048, 4><<<1024, 512, 0, stream>>>(H1, WFC2T, fc2_b, X2, out, nullptr);
}

// Round 24
// 811.882 us; speedup vs baseline: 1.1033x; 1.0065x over previous
//
#include <hip/hip_runtime.h>
#include <hip/hip_bf16.h>

using f32x4  = __attribute__((ext_vector_type(4))) float;
using bf16x8 = __attribute__((ext_vector_type(8))) short;
using short8 = __attribute__((ext_vector_type(8))) short;
using s16x4  = __attribute__((ext_vector_type(4))) short;

#define DEVINL __device__ __forceinline__

DEVINL short f2bf(float f) {
  unsigned u = __builtin_bit_cast(unsigned, f);
  u += 0x7fffu + ((u >> 16) & 1u);          // RNE
  return (short)(u >> 16);
}
DEVINL float bf2f(short h) {
  return __builtin_bit_cast(float, (unsigned)((unsigned short)h) << 16);
}

// tanh-approx GELU in sigmoid form: 0.5v(1+tanh(u)) == v/(1+exp(-2u))
DEVINL float gelu_fast(float v) {
  float t = __expf(-1.5957691216057308f * (v + 0.044715f * v * v * v));
  return v * __builtin_amdgcn_rcpf(1.0f + t);
}

#define GLDS16(g, l) __builtin_amdgcn_global_load_lds( \
    (const __attribute__((address_space(1))) void*)(g), \
    (__attribute__((address_space(3))) void*)(l), 16, 0, 0)

// ---------------------------------------------------------------- fused prep (LDS-tiled transposes)
__global__ __launch_bounds__(256)
void prep(const float* __restrict__ qkv_w, const float* __restrict__ proj_w,
          const float* __restrict__ fc1_w, const float* __restrict__ fc2_w,
          const float* __restrict__ rpb,
          short* __restrict__ WQKVT, short* __restrict__ WPROJT,
          short* __restrict__ WFC1T, short* __restrict__ WFC2T,
          float* __restrict__ BIASF) {
  __shared__ float tile[64][65];
  const int b = blockIdx.x, t = threadIdx.x;
  const float* src; short* dst; int R, C, boff;
  if (b < 192)      { src = qkv_w;  dst = WQKVT;  R = 512;  C = 1536; boff = b; }
  else if (b < 256) { src = proj_w; dst = WPROJT; R = 512;  C = 512;  boff = b - 192; }
  else if (b < 512) { src = fc1_w;  dst = WFC1T;  R = 512;  C = 2048; boff = b - 256; }
  else if (b < 768) { src = fc2_w;  dst = WFC2T;  R = 2048; C = 512;  boff = b - 512; }
  else {
    int idx = (b - 768) * 256 + t;   // BIASF[head][n][m], 65536 elems
    int head = idx >> 12, n = (idx >> 6) & 63, m = idx & 63;
    int i1 = n >> 3, j1 = n & 7, i2 = m >> 3, j2 = m & 7;
    BIASF[idx] = rpb[((i1 - i2 + 7) * 15 + (j1 - j2 + 7)) * 16 + head];
    return;
  }
  const int tc = C >> 6;
  const int r0 = (boff / tc) * 64, c0 = (boff % tc) * 64;
  const int row4 = t >> 6, col = t & 63;
#pragma unroll
  for (int rep = 0; rep < 16; ++rep) {
    const int row = rep * 4 + row4;
    tile[row][col] = src[(size_t)(r0 + row) * C + c0 + col];
  }
  __syncthreads();
#pragma unroll
  for (int rep = 0; rep < 16; ++rep) {
    const int crow = rep * 4 + row4;
    dst[(size_t)(c0 + crow) * R + r0 + col] = f2bf(tile[col][crow]);
  }
}

// ---------------------------------------------------------------- LayerNorm (fp32 in, bf16 out)
template<int REMAP>
__global__ __launch_bounds__(256)
void ln_kernel(const float* __restrict__ X, const float* __restrict__ gamma,
               const float* __restrict__ beta, short* __restrict__ OUT) {
  const int lane = threadIdx.x & 63;
  const int wid  = threadIdx.x >> 6;
  const int t    = blockIdx.x * 4 + wid;
  const float* xp = X + (size_t)t * 512 + lane * 8;
  float4 a = *(const float4*)xp;
  float4 b = *(const float4*)(xp + 4);
  float s = a.x + a.y + a.z + a.w + b.x + b.y + b.z + b.w;
  float q = a.x*a.x + a.y*a.y + a.z*a.z + a.w*a.w
          + b.x*b.x + b.y*b.y + b.z*b.z + b.w*b.w;
#pragma unroll
  for (int d = 1; d < 64; d <<= 1) { s += __shfl_xor(s, d); q += __shfl_xor(q, d); }
  float mean = s * (1.0f / 512.0f);
  float var  = q * (1.0f / 512.0f) - mean * mean;
  float rstd = rsqrtf(var + 1e-5f);
  float4 g0 = *(const float4*)(gamma + lane * 8);
  float4 g1 = *(const float4*)(gamma + lane * 8 + 4);
  float4 b0 = *(const float4*)(beta + lane * 8);
  float4 b1 = *(const float4*)(beta + lane * 8 + 4);
  short8 o;
  o[0] = f2bf((a.x - mean) * rstd * g0.x + b0.x);
  o[1] = f2bf((a.y - mean) * rstd * g0.y + b0.y);
  o[2] = f2bf((a.z - mean) * rstd * g0.z + b0.z);
  o[3] = f2bf((a.w - mean) * rstd * g0.w + b0.w);
  o[4] = f2bf((b.x - mean) * rstd * g1.x + b1.x);
  o[5] = f2bf((b.y - mean) * rstd * g1.y + b1.y);
  o[6] = f2bf((b.z - mean) * rstd * g1.z + b1.z);
  o[7] = f2bf((b.w - mean) * rstd * g1.w + b1.w);
  size_t orow;
  if (REMAP) {
    int bb = t >> 12, l = t & 4095, hh = l >> 6, ww = l & 63;
    int hs = (hh + 60) & 63, ws2 = (ww + 60) & 63;   // (coord - 4) mod 64
    orow = (size_t)(bb * 64 + (hs >> 3) * 8 + (ws2 >> 3)) * 64 + (hs & 7) * 8 + (ws2 & 7);
  } else {
    orow = (size_t)t;
  }
  *(short8*)(OUT + orow * 512 + lane * 8) = o;
}

// ---------------------------------------------------------------- LayerNorm (bf16 in, bf16 out)
__global__ __launch_bounds__(256)
void ln_bf16(const short* __restrict__ X, const float* __restrict__ gamma,
             const float* __restrict__ beta, short* __restrict__ OUT) {
  const int lane = threadIdx.x & 63;
  const int wid  = threadIdx.x >> 6;
  const int t    = blockIdx.x * 4 + wid;
  short8 v = *(const short8*)(X + (size_t)t * 512 + lane * 8);
  float f[8];
#pragma unroll
  for (int k = 0; k < 8; ++k) f[k] = bf2f(v[k]);
  float s = 0.f, q = 0.f;
#pragma unroll
  for (int k = 0; k < 8; ++k) { s += f[k]; q += f[k] * f[k]; }
#pragma unroll
  for (int d = 1; d < 64; d <<= 1) { s += __shfl_xor(s, d); q += __shfl_xor(q, d); }
  float mean = s * (1.0f / 512.0f);
  float var  = q * (1.0f / 512.0f) - mean * mean;
  float rstd = rsqrtf(var + 1e-5f);
  float4 g0 = *(const float4*)(gamma + lane * 8);
  float4 g1 = *(const float4*)(gamma + lane * 8 + 4);
  float4 b0 = *(const float4*)(beta + lane * 8);
  float4 b1 = *(const float4*)(beta + lane * 8 + 4);
  short8 o;
  o[0] = f2bf((f[0] - mean) * rstd * g0.x + b0.x);
  o[1] = f2bf((f[1] - mean) * rstd * g0.y + b0.y);
  o[2] = f2bf((f[2] - mean) * rstd * g0.z + b0.z);
  o[3] = f2bf((f[3] - mean) * rstd * g0.w + b0.w);
  o[4] = f2bf((f[4] - mean) * rstd * g1.x + b1.x);
  o[5] = f2bf((f[5] - mean) * rstd * g1.y + b1.y);
  o[6] = f2bf((f[6] - mean) * rstd * g1.z + b1.z);
  o[7] = f2bf((f[7] - mean) * rstd * g1.w + b1.w);
  *(short8*)(OUT + (size_t)t * 512 + lane * 8) = o;
}

// ---------------------------------------------------------------- attention core
__global__ __launch_bounds__(256)
void attn_core(const short* __restrict__ Q, const short* __restrict__ Kb,
               const short* __restrict__ VT, const float* __restrict__ BIASF,
               short* __restrict__ AOUT) {
  __shared__ short P[4][4096];
  const int tid = threadIdx.x, lane = tid & 63, wid = tid >> 6;
  const int lr = lane & 15, lg = lane >> 4;
  const int gw = blockIdx.x * 4 + wid;
  const int win = gw >> 4, head = gw & 15;
  const int wimg = win & 63, wh = wimg >> 3, ww = wimg & 7;
  const size_t qbase = (size_t)win * 64 * 512 + head * 32;
  short* Pb = P[wid];

  bf16x8 aq[4], bk[4];
#pragma unroll
  for (int tm = 0; tm < 4; ++tm) aq[tm] = *(const bf16x8*)(Q  + qbase + (size_t)(tm * 16 + lr) * 512 + lg * 8);
#pragma unroll
  for (int tn = 0; tn < 4; ++tn) bk[tn] = *(const bf16x8*)(Kb + qbase + (size_t)(tn * 16 + lr) * 512 + lg * 8);
  f32x4 sa[4][4] = {};
#pragma unroll
  for (int tm = 0; tm < 4; ++tm)
#pragma unroll
    for (int tn = 0; tn < 4; ++tn)
      sa[tm][tn] = __builtin_amdgcn_mfma_f32_16x16x32_bf16(aq[tm], bk[tn], sa[tm][tn], 0, 0, 0);

  const float* bias_h = BIASF + head * 4096;
  float inv[4][4];
#pragma unroll
  for (int tm = 0; tm < 4; ++tm) {
#pragma unroll
    for (int e = 0; e < 4; ++e) {
      const int n = tm * 16 + lg * 4 + e;
      const int i1 = n >> 3, j1 = n & 7;
      const int rh1 = (wh == 7) ? 1 + (i1 >> 2) : 0;
      const int rw1 = (ww == 7) ? 1 + (j1 >> 2) : 0;
      float v[4];
      float mx = -3.0e38f;
#pragma unroll
      for (int tn = 0; tn < 4; ++tn) {
        const int m = tn * 16 + lr;
        const int mi = (m >> 3), mj = m & 7;
        const int rh2 = (wh == 7) ? 1 + (mi >> 2) : 0;
        const int rw2 = (ww == 7) ? 1 + (mj >> 2) : 0;
        float val = sa[tm][tn][e] + bias_h[n * 64 + m]
                  + ((rh1 != rh2 || rw1 != rw2) ? -100.0f : 0.0f);
        v[tn] = val;
        mx = fmaxf(mx, val);
      }
#pragma unroll
      for (int d = 1; d < 16; d <<= 1) mx = fmaxf(mx, __shfl_xor(mx, d));
      float sum = 0.f;
#pragma unroll
      for (int tn = 0; tn < 4; ++tn) { v[tn] = __expf(v[tn] - mx); sum += v[tn]; }
#pragma unroll
      for (int d = 1; d < 16; d <<= 1) sum += __shfl_xor(sum, d);
      inv[tm][e] = 1.0f / sum;
      const int sw = (n & 7) << 3;
#pragma unroll
      for (int tn = 0; tn < 4; ++tn) Pb[n * 64 + ((tn * 16 + lr) ^ sw)] = f2bf(v[tn]);
    }
  }
  __syncthreads();

  f32x4 oa[4][2] = {};
  const short* vt = VT + (size_t)win * 32768 + head * 2048;
#pragma unroll
  for (int ks = 0; ks < 2; ++ks) {
    bf16x8 pa[4], bv[2];
#pragma unroll
    for (int tm = 0; tm < 4; ++tm) {
      const int r = tm * 16 + lr;
      pa[tm] = *(const bf16x8*)(Pb + r * 64 + ((ks * 32 + lg * 8) ^ ((r & 7) << 3)));
    }
#pragma unroll
    for (int t2 = 0; t2 < 2; ++t2) bv[t2] = *(const bf16x8*)(vt + (t2 * 16 + lr) * 64 + ks * 32 + lg * 8);
#pragma unroll
    for (int tm = 0; tm < 4; ++tm)
#pragma unroll
      for (int t2 = 0; t2 < 2; ++t2)
        oa[tm][t2] = __builtin_amdgcn_mfma_f32_16x16x32_bf16(pa[tm], bv[t2], oa[tm][t2], 0, 0, 0);
  }
#pragma unroll
  for (int tm = 0; tm < 4; ++tm)
#pragma unroll
    for (int t2 = 0; t2 < 2; ++t2)
#pragma unroll
      for (int e = 0; e < 4; ++e) {
        const int n = tm * 16 + lg * 4 + e;
        AOUT[((size_t)win * 64 + n) * 512 + head * 32 + t2 * 16 + lr] = f2bf(oa[tm][t2][e] * inv[tm][e]);
      }
}

// ---------------------------------------------------------------- 256x128 GEMM, BK=64 (R17 structure)
// EPI 0 (proj): C[tok][out] -> X2B bf16 window-reversed + x(fp32) residual + bias
// EPI 1 (fc1, swapped): C[h][tok] -> H1[tok][2048] bf16 gelu, packed s16x4
// EPI 2 (fc2): C[tok][out] -> out fp32 = acc + bias + X2B(bf16) residual
// EPI 3 (qkv, swapped): LDS-coalesced stores — Q/K [tok][oc] 64B bursts,
//                       V^T [d][tok] 128B bursts (sector-exact).
template<int EPI, int K, int NX>
__global__ __launch_bounds__(512, 1)
void gemmBK64(const short* __restrict__ Aa, const short* __restrict__ Bb,
              const float* __restrict__ bias, const float* __restrict__ resid,
              const short* __restrict__ residh,
              float* __restrict__ outf, short* __restrict__ outh) {
  constexpr int NT = K / 64;
  __shared__ short L[24576];   // A bytes [0,32768), B bytes [32768,49152)
  const int tid = threadIdx.x;
  const int lane = tid & 63, wid = tid >> 6;
  const int lr = lane & 15, lg = lane >> 4;
  const int wm = wid >> 1, wn = wid & 1;

  // XCD-aware bijective swizzle (all grids are multiples of 8)
  const int nwg = gridDim.x;
  const int id = blockIdx.x;
  const int id2 = (id & 7) * (nwg >> 3) + (id >> 3);
  const bool swapped = (EPI == 1 || EPI == 3);
  const int mt    = swapped ? (id2 % NX) : (id2 / NX);
  const int ntile = swapped ? (id2 / NX) : (id2 % NX);
  const int m0 = mt * 256, n0 = ntile * 128;

  // staging geometry: instr c -> row c*64 + rr, phys slot tid&7
  const int rr = tid >> 3;                                   // 0..63
  const int ss = ((tid & 7) ^ (rr & 7)) * 8;                 // swizzled source col (elems)
  const short* pA = Aa + (size_t)(m0 + rr) * K + ss;
  const short* pB = Bb + (size_t)(n0 + rr) * K + ss;
  char* Ld = (char*)L + tid * 16;

  // frag read bases (slot = (kk*4+lg)^(lr&7))
  const int xr = lr & 7;
  const char* rA0 = (char*)L + (wm * 64 + lr) * 128 + ((lg ^ xr) << 4);
  const char* rA1 = (char*)L + (wm * 64 + lr) * 128 + (((4 + lg) ^ xr) << 4);
  const char* rB0 = (char*)L + 32768 + (wn * 64 + lr) * 128 + ((lg ^ xr) << 4);
  const char* rB1 = (char*)L + 32768 + (wn * 64 + lr) * 128 + (((4 + lg) ^ xr) << 4);

  f32x4 acc[4][4] = {};
  for (int kt = 0; kt < NT; ++kt) {
    const int ko = kt * 64;
    GLDS16(pA + ko,                    Ld);
    GLDS16(pA + ko + (size_t)64  * K,  Ld + 8192);
    GLDS16(pA + ko + (size_t)128 * K,  Ld + 16384);
    GLDS16(pA + ko + (size_t)192 * K,  Ld + 24576);
    GLDS16(pB + ko,                    Ld + 32768);
    GLDS16(pB + ko + (size_t)64  * K,  Ld + 40960);
    __syncthreads();
    bf16x8 a[4], b[4];
#pragma unroll
    for (int i = 0; i < 4; ++i) a[i] = *(const bf16x8*)(rA0 + i * 2048);
#pragma unroll
    for (int j = 0; j < 4; ++j) b[j] = *(const bf16x8*)(rB0 + j * 2048);
#pragma unroll
    for (int i = 0; i < 4; ++i)
#pragma unroll
      for (int j = 0; j < 4; ++j)
        acc[i][j] = __builtin_amdgcn_mfma_f32_16x16x32_bf16(a[i], b[j], acc[i][j], 0, 0, 0);
#pragma unroll
    for (int i = 0; i < 4; ++i) a[i] = *(const bf16x8*)(rA1 + i * 2048);
#pragma unroll
    for (int j = 0; j < 4; ++j) b[j] = *(const bf16x8*)(rB1 + j * 2048);
#pragma unroll
    for (int i = 0; i < 4; ++i)
#pragma unroll
      for (int j = 0; j < 4; ++j)
        acc[i][j] = __builtin_amdgcn_mfma_f32_16x16x32_bf16(a[i], b[j], acc[i][j], 0, 0, 0);
    __syncthreads();
  }

  // ---- epilogue
  if (EPI == 1) {
#pragma unroll
    for (int i = 0; i < 4; ++i) {
      const int h0 = m0 + wm * 64 + i * 16 + lg * 4;
      const float4 bi = *(const float4*)(bias + h0);
#pragma unroll
      for (int j = 0; j < 4; ++j) {
        const int tok = n0 + wn * 64 + j * 16 + lr;
        s16x4 o;
        o[0] = f2bf(gelu_fast(acc[i][j][0] + bi.x));
        o[1] = f2bf(gelu_fast(acc[i][j][1] + bi.y));
        o[2] = f2bf(gelu_fast(acc[i][j][2] + bi.z));
        o[3] = f2bf(gelu_fast(acc[i][j][3] + bi.w));
        *(s16x4*)(outh + (size_t)tok * 2048 + h0) = o;
      }
    }
  } else if (EPI == 0) {
    // proj: X2B bf16 at window-reversed row, + x (fp32) residual
#pragma unroll
    for (int j = 0; j < 4; ++j) {
      const int col = n0 + wn * 64 + j * 16 + lr;
      const float bc = bias[col];
#pragma unroll
      for (int i = 0; i < 4; ++i)
#pragma unroll
        for (int e = 0; e < 4; ++e) {
          const int row = m0 + wm * 64 + i * 16 + lg * 4 + e;
          float v = acc[i][j][e] + bc;
          const int wv = row >> 6, n = row & 63;
          const int bb = wv >> 6, wi = wv & 63;
          const int hs = (wi >> 3) * 8 + (n >> 3), ws2 = (wi & 7) * 8 + (n & 7);
          const int hh = (hs + 4) & 63, wwp = (ws2 + 4) & 63;
          const size_t orow = (size_t)bb * 4096 + hh * 64 + wwp;
          outh[orow * 512 + col] = f2bf(resid[orow * 512 + col] + v);
        }
    }
  } else if (EPI == 2) {
    // fc2: out fp32 = acc + bias + X2B (bf16) residual
#pragma unroll
    for (int j = 0; j < 4; ++j) {
      const int col = n0 + wn * 64 + j * 16 + lr;
      const float bc = bias[col];
#pragma unroll
      for (int i = 0; i < 4; ++i)
#pragma unroll
        for (int e = 0; e < 4; ++e) {
          const int row = m0 + wm * 64 + i * 16 + lg * 4 + e;
          outf[(size_t)row * 512 + col] = acc[i][j][e] + bc + bf2f(residh[(size_t)row * 512 + col]);
        }
    }
  } else {
    // qkv swapped, LDS-coalesced (wave-private scratch)
    const int seg = m0 >> 9;
    const float qs = (seg == 0) ? 0.17677669529663687f : 1.0f;
    char* W = (char*)L + wid * 4352;
    const int tok0w = n0 + wn * 64;
    const int oc0w  = m0 + wm * 64;
#pragma unroll
    for (int h = 0; h < 2; ++h) {
#pragma unroll
      for (int ii = 0; ii < 2; ++ii) {
        const int i = 2 * h + ii;
        const float4 bi = *(const float4*)(bias + oc0w + i * 16 + lg * 4);
        const float bb[4] = {bi.x, bi.y, bi.z, bi.w};
#pragma unroll
        for (int j = 0; j < 4; ++j)
#pragma unroll
          for (int e = 0; e < 4; ++e) {
            const short hv = f2bf((acc[i][j][e] + bb[e]) * qs);
            if (seg == 2)
              *(short*)(W + (ii * 16 + lg * 4 + e) * 132 + (j * 16 + lr) * 2) = hv;   // [d][tok+pad]
            else
              *(short*)(W + (j * 16 + lr) * 68 + (ii * 16 + lg * 4 + e) * 2) = hv;    // [tok][oc+pad]
          }
      }
      if (seg == 2) {
#pragma unroll
        for (int p = 0; p < 4; ++p) {
          const int dl = p * 8 + (lane >> 3);
          const bf16x8 v = *(const bf16x8*)(W + dl * 132 + (lane & 7) * 16);
          const int dglob = (oc0w - 1024) + h * 32 + dl;
          *(bf16x8*)(outh + 67108864 +
                     (size_t)((tok0w >> 6) * 16 + (dglob >> 5)) * 2048 +
                     (dglob & 31) * 64 + (lane & 7) * 8) = v;
        }
      } else {
#pragma unroll
        for (int p = 0; p < 4; ++p) {
          const int tokl = p * 16 + (lane >> 2);
          const bf16x8 v = *(const bf16x8*)(W + tokl * 68 + (lane & 3) * 16);
          short* dst = (seg == 0) ? outh : (outh + 33554432 - 512);
          *(bf16x8*)(dst + (size_t)(tok0w + tokl) * 512 + oc0w + h * 32 + (lane & 3) * 8) = v;
        }
      }
    }
  }
}

// ---------------------------------------------------------------- launch
extern "C" void kernel_launch(void* const* d_in, const int* in_sizes, int n_in,
                              void* d_out, int out_size, void* d_ws, size_t ws_size,
                              hipStream_t stream) {
  (void)in_sizes; (void)n_in; (void)out_size; (void)ws_size;
  const float* x      = (const float*)d_in[0];
  const float* g1     = (const float*)d_in[1];
  const float* b1     = (const float*)d_in[2];
  const float* qkv_w  = (const float*)d_in[3];
  const float* qkv_b  = (const float*)d_in[4];
  const float* proj_w = (const float*)d_in[5];
  const float* proj_b = (const float*)d_in[6];
  const float* rpb    = (const float*)d_in[7];
  const float* g2     = (const float*)d_in[8];
  const float* b2     = (const float*)d_in[9];
  const float* fc1_w  = (const float*)d_in[10];
  const float* fc1_b  = (const float*)d_in[11];
  const float* fc2_w  = (const float*)d_in[12];
  const float* fc2_b  = (const float*)d_in[13];
  float* out = (float*)d_out;
  char* ws = (char*)d_ws;

  short* WQKVT  = (short*)(ws);                 // [1536][512] bf16   1.5MB
  short* WPROJT = (short*)(ws + 1572864);       // [512][512]         0.5MB
  short* WFC1T  = (short*)(ws + 2097152);       // [2048][512]        2MB
  short* WFC2T  = (short*)(ws + 4194304);       // [512][2048]        2MB
  short* X2B    = (short*)(ws + 6291456);       // [65536][512] bf16  64MB
  float* BIASF  = (float*)(ws + 73400320);      // 256KB (separate; X2B alias unsafe with bf16)
  short* ATT    = (short*)(ws + 140509184);     // [65536][512] bf16  64MB (X2N reuse)
  short* XW     = (short*)(ws + 207618048);     // [65536][512] bf16  64MB
  short* QB     = (short*)(ws + 274726912);     // Q|K|VT 3x64MB
  short* H1     = XW;                           // [65536][2048] bf16 256MB over XW+QB (dead)
  short* X2N    = ATT;

  prep<<<1024, 256, 0, stream>>>(qkv_w, proj_w, fc1_w, fc2_w, rpb,
                                 WQKVT, WPROJT, WFC1T, WFC2T, BIASF);

  ln_kernel<1><<<16384, 256, 0, stream>>>(x, g1, b1, XW);
  // qkv SWAPPED: A=WQKVT (6 m-tiles), B=XW (512 n-tiles) -> C[oc][tok], LDS-coalesced stores
  gemmBK64<3, 512, 6><<<3072, 512, 0, stream>>>(WQKVT, XW, qkv_b, nullptr, nullptr, nullptr, QB);
  attn_core<<<4096, 256, 0, stream>>>(QB, QB + 33554432, QB + 67108864, BIASF, ATT);
  // proj: A=ATT (256 m-tiles), BT=WPROJT (4 n-tiles) -> X2B bf16 (window-reverse + x resid)
  gemmBK64<0, 512, 4><<<1024, 512, 0, stream>>>(ATT, WPROJT, proj_b, x, nullptr, nullptr, X2B);
  ln_bf16<<<16384, 256, 0, stream>>>(X2B, g2, b2, X2N);
  // fc1 swapped: A=W1T (8 m-tiles), B=X2N (512 n-tiles) -> H1[tok][2048]
  gemmBK64<1, 512, 8><<<4096, 512, 0, stream>>>(WFC1T, X2N, fc1_b, nullptr, nullptr, nullptr, H1);
  // fc2: A=H1 (256 m-tiles), BT=W2T (4 n-tiles) -> out fp32 + bias + X2B resid
  gemmBK64<2, 2048, 4><<<1024, 512, 0, stream>>>(H1, WFC2T, fc2_b, nullptr, X2B, out, nullptr);
}